// Round 9
// baseline (343.505 us; speedup 1.0000x reference)
//
#include <hip/hip_runtime.h>
#include <stdint.h>

#define BATCH 32
#define CCH   512
#define NPIX  1024
#define HEADS 8
#define QKV_M 1536   // q rows 0-511, k rows 512-1023, v rows 1024-1535

typedef short bf16x8 __attribute__((ext_vector_type(8)));
typedef float f32x4 __attribute__((ext_vector_type(4)));
typedef unsigned short u16x8 __attribute__((ext_vector_type(8)));

__device__ inline float bf2f(unsigned short u) {
  union { float f; uint32_t i; } t; t.i = ((uint32_t)u) << 16; return t.f;
}
__device__ inline unsigned short f2bf(float f) {
  union { float f; uint32_t u; } t; t.f = f;
  uint32_t u = t.u;
  return (unsigned short)((u + 0x7FFFu + ((u >> 16) & 1u)) >> 16);
}

// async global->LDS, 16B per lane; LDS dest = wave-uniform base + lane*16
__device__ inline void gl_lds16(const unsigned short* g, unsigned short* l) {
  __builtin_amdgcn_global_load_lds(
      (const __attribute__((address_space(1))) uint32_t*)g,
      (__attribute__((address_space(3))) uint32_t*)l, 16, 0, 0);
}

// ---------------- prep_w: weights fp32->bf16 AND zero s1/s2 ------------------
// (round-8: absorbs the hipMemsetAsync dispatch; block 0 zeroes 4KB of stats)
__global__ void prep_w(const float* __restrict__ Wq, const float* __restrict__ Wk,
                       const float* __restrict__ Wv, const float* __restrict__ Wp,
                       unsigned short* __restrict__ wcat,
                       unsigned short* __restrict__ wpb,
                       float* __restrict__ s1, float* __restrict__ s2) {
  if (blockIdx.x == 0) {
    const f32x4 z4 = {0.f, 0.f, 0.f, 0.f};
    if (threadIdx.x < 128) ((f32x4*)s1)[threadIdx.x] = z4;
    else ((f32x4*)s2)[threadIdx.x - 128] = z4;
  }
  int i = (blockIdx.x * 256 + threadIdx.x) * 4;   // over CCH*CCH = 262144
  union { ushort4 u4; unsigned short s[4]; } o;
  f32x4 a;
  a = *(const f32x4*)&Wq[i];
  for (int j = 0; j < 4; j++) o.s[j] = f2bf(a[j]);
  *(ushort4*)&wcat[i] = o.u4;
  a = *(const f32x4*)&Wk[i];
  for (int j = 0; j < 4; j++) o.s[j] = f2bf(a[j]);
  *(ushort4*)&wcat[CCH * CCH + i] = o.u4;
  a = *(const f32x4*)&Wv[i];
  for (int j = 0; j < 4; j++) o.s[j] = f2bf(a[j]);
  *(ushort4*)&wcat[2 * CCH * CCH + i] = o.u4;
  a = *(const f32x4*)&Wp[i];
  for (int j = 0; j < 4; j++) o.s[j] = f2bf(a[j]);
  *(ushort4*)&wpb[i] = o.u4;
}

// ================= device bodies (shared by fused + fallback kernels) ========

// depthwise 3x3 stats for one (b,c) plane; plane = 1024-float LDS scratch
__device__ __forceinline__ void stats_body(const float* __restrict__ xp,
                                           const float* __restrict__ wgt, int c,
                                           float* __restrict__ s1,
                                           float* __restrict__ s2,
                                           float* __restrict__ plane,
                                           float* __restrict__ r1,
                                           float* __restrict__ r2) {
  *(f32x4*)&plane[threadIdx.x * 4] = *(const f32x4*)&xp[threadIdx.x * 4];
  __syncthreads();
  float w[9];
  for (int i = 0; i < 9; i++) w[i] = wgt[c * 9 + i];
  float a1 = 0.f, a2 = 0.f;
  for (int pi = 0; pi < 4; pi++) {
    int p = threadIdx.x + pi * 256;
    int h = p >> 5, wc = p & 31;
    float v = 0.f;
    for (int dh = -1; dh <= 1; dh++)
      for (int dw = -1; dw <= 1; dw++) {
        int hh = h + dh, ww = wc + dw;
        if (hh >= 0 && hh < 32 && ww >= 0 && ww < 32)
          v += w[(dh + 1) * 3 + dw + 1] * plane[hh * 32 + ww];
      }
    a1 += v; a2 += v * v;
  }
  for (int off = 32; off > 0; off >>= 1) {
    a1 += __shfl_down(a1, off);
    a2 += __shfl_down(a2, off);
  }
  int wv = threadIdx.x >> 6;
  if ((threadIdx.x & 63) == 0) { r1[wv] = a1; r2[wv] = a2; }
  __syncthreads();
  if (threadIdx.x == 0) {
    atomicAdd(&s1[c], r1[0] + r1[1] + r1[2] + r1[3]);
    atomicAdd(&s2[c], r2[0] + r2[1] + r2[2] + r2[3]);
  }
}

// 64x64 transpose tile: fp32 [C,N] -> bf16 [N,C]; tile = [64][65] f32 LDS
__device__ __forceinline__ void transpose_body(const float* __restrict__ inb,
                                               unsigned short* __restrict__ outb,
                                               int p0, int c0,
                                               float (*tile)[65]) {
  const int t = threadIdx.x;
  const int cr = t >> 2, tl = t & 3;
#pragma unroll
  for (int j = 0; j < 4; ++j) {
    const int off = j * 16 + tl * 4;
    f32x4 v = *(const f32x4*)&inb[(size_t)(c0 + cr) * NPIX + p0 + off];
    tile[cr][off + 0] = v[0];
    tile[cr][off + 1] = v[1];
    tile[cr][off + 2] = v[2];
    tile[cr][off + 3] = v[3];
  }
  __syncthreads();
  const int pr = t >> 3, cc = (t & 7) * 8;
#pragma unroll
  for (int pass = 0; pass < 2; ++pass) {
    const int p = pr + pass * 32;
    union { u16x8 v; unsigned short s[8]; } o;
#pragma unroll
    for (int j = 0; j < 8; ++j) o.s[j] = f2bf(tile[cc + j][p]);
    *(u16x8*)&outb[(size_t)(p0 + p) * CCH + c0 + cc] = o.v;
  }
}

// gate for one (b,c) plane: V *= SiLU(BN(conv(x)))
__device__ __forceinline__ void gate_body(const float* __restrict__ xp,
                                          const float* __restrict__ wgt, int c,
                                          const float* __restrict__ s1,
                                          const float* __restrict__ s2,
                                          const float* __restrict__ gamma,
                                          const float* __restrict__ beta,
                                          unsigned short* __restrict__ vbase,
                                          float* __restrict__ plane) {
  *(f32x4*)&plane[threadIdx.x * 4] = *(const f32x4*)&xp[threadIdx.x * 4];
  __syncthreads();
  float w[9];
  for (int i = 0; i < 9; i++) w[i] = wgt[c * 9 + i];
  const float invn = 1.f / 32768.f;
  float mean = s1[c] * invn;
  float var = fmaxf(s2[c] * invn - mean * mean, 0.f);
  float rstd = rsqrtf(var + 1e-5f);
  float ga = gamma[c], be = beta[c];
  const int t = threadIdx.x;
  const int h = t >> 3, w0 = (t & 7) * 4;
  unsigned short* vp = vbase + h * 32 + w0;
  union { ushort4 q; unsigned short s[4]; } vv;
  vv.q = *(const ushort4*)vp;
#pragma unroll
  for (int i = 0; i < 4; ++i) {
    const int wc = w0 + i;
    float val = 0.f;
    for (int dh = -1; dh <= 1; dh++)
      for (int dw = -1; dw <= 1; dw++) {
        int hh = h + dh, ww = wc + dw;
        if (hh >= 0 && hh < 32 && ww >= 0 && ww < 32)
          val += w[(dh + 1) * 3 + dw + 1] * plane[hh * 32 + ww];
      }
    float g = (val - mean) * rstd * ga + be;
    float sg = g / (1.f + __expf(-g));      // SiLU
    vv.s[i] = f2bf(bf2f(vv.s[i]) * sg);
  }
  *(ushort4*)vp = vv.q;
}

// attn_s body (256 thr): S=QK^T + fused l2norm, softmax -> P[bh]
__device__ __forceinline__ void attn_s_body(const unsigned short* __restrict__ qkv,
                                            const float* __restrict__ temp,
                                            unsigned short* __restrict__ P, int bh,
                                            float (*Sf)[65],
                                            float* qq, float* kk,
                                            float* invq, float* invk,
                                            float (*redm)[64], float (*reds)[64]) {
  int b = bh >> 3, h = bh & 7;
  const unsigned short* Q = qkv + ((size_t)b * QKV_M + h * 64) * NPIX;
  const unsigned short* K = Q + (size_t)CCH * NPIX;
  int tid = threadIdx.x, lane = tid & 63, wave = tid >> 6;
  int quad = lane >> 4, l16 = lane & 15;

  f32x4 zero = {0.f, 0.f, 0.f, 0.f};
  f32x4 acc[4], accQ = zero, accK = zero;
  for (int j = 0; j < 4; j++) acc[j] = zero;
  for (int n0 = 0; n0 < NPIX; n0 += 32) {
    bf16x8 a  = *(const bf16x8*)&Q[(size_t)(wave * 16 + l16) * NPIX + n0 + quad * 8];
    bf16x8 ak = *(const bf16x8*)&K[(size_t)(wave * 16 + l16) * NPIX + n0 + quad * 8];
    accQ = __builtin_amdgcn_mfma_f32_16x16x32_bf16(a, a, accQ, 0, 0, 0);
    accK = __builtin_amdgcn_mfma_f32_16x16x32_bf16(ak, ak, accK, 0, 0, 0);
    for (int j = 0; j < 4; j++) {
      bf16x8 bb = *(const bf16x8*)&K[(size_t)(j * 16 + l16) * NPIX + n0 + quad * 8];
      acc[j] = __builtin_amdgcn_mfma_f32_16x16x32_bf16(a, bb, acc[j], 0, 0, 0);
    }
  }
  for (int j = 0; j < 4; j++)
    for (int r = 0; r < 4; r++)
      Sf[wave * 16 + quad * 4 + r][j * 16 + l16] = acc[j][r];
  for (int r = 0; r < 4; r++)
    if (l16 == quad * 4 + r) {
      qq[wave * 16 + l16] = accQ[r];
      kk[wave * 16 + l16] = accK[r];
    }
  __syncthreads();
  if (tid < 64) invq[tid] = 1.f / fmaxf(sqrtf(qq[tid]), 1e-12f);
  else if (tid < 128) invk[tid - 64] = 1.f / fmaxf(sqrtf(kk[tid - 64]), 1e-12f);
  __syncthreads();

  int row = tid & 63, seg = tid >> 6;
  float fq = temp[h] * invq[row];
  float v[16], pm = -1e30f;
  for (int i = 0; i < 16; i++) {
    v[i] = Sf[row][seg * 16 + i] * fq * invk[seg * 16 + i];
    pm = fmaxf(pm, v[i]);
  }
  redm[seg][row] = pm;
  __syncthreads();
  float m = fmaxf(fmaxf(redm[0][row], redm[1][row]),
                  fmaxf(redm[2][row], redm[3][row]));
  float ps = 0.f;
  for (int i = 0; i < 16; i++) { v[i] = __expf(v[i] - m); ps += v[i]; }
  reds[seg][row] = ps;
  __syncthreads();
  float inv = 1.f / (reds[0][row] + reds[1][row] + reds[2][row] + reds[3][row]);
  union { uint4 q4[2]; unsigned short s[16]; } u;
  for (int i = 0; i < 16; i++) u.s[i] = f2bf(v[i] * inv);
  unsigned short* Pp = P + ((size_t)bh * 64 + row) * 64 + seg * 16;
  *(uint4*)&Pp[0] = u.q4[0];
  *(uint4*)&Pp[8] = u.q4[1];
}

// ================= fused kernels (round-8 dispatch-count experiment) =========
// stats_transpose: blocks [0, 16384) = dw_stats(c,b); [16384, 20480) = transpose
__global__ void stats_transpose(const float* __restrict__ x,
                                const float* __restrict__ wgt,
                                float* __restrict__ s1, float* __restrict__ s2,
                                unsigned short* __restrict__ xT) {
  __shared__ float tile[64][65];
  __shared__ float r1[4], r2[4];
  const int bid = blockIdx.x;
  if (bid < CCH * BATCH) {
    const int c = bid & (CCH - 1), b = bid >> 9;
    stats_body(x + ((size_t)b * CCH + c) * NPIX, wgt, c, s1, s2,
               &tile[0][0], r1, r2);
  } else {
    const int j = bid - CCH * BATCH;
    const int p0 = (j & 15) * 64, c0 = ((j >> 4) & 7) * 64, b = j >> 7;
    transpose_body(x + (size_t)b * CCH * NPIX, xT + (size_t)b * NPIX * CCH,
                   p0, c0, tile);
  }
}

// attn_gate: blocks [0, 16384) = gate(c,b); [16384, 16640) = attn_s(bh)
__global__ void attn_gate(unsigned short* __restrict__ qkv,
                          const float* __restrict__ temp,
                          unsigned short* __restrict__ P,
                          const float* __restrict__ x,
                          const float* __restrict__ wgt,
                          const float* __restrict__ s1,
                          const float* __restrict__ s2,
                          const float* __restrict__ gamma,
                          const float* __restrict__ beta) {
  __shared__ float Sf[64][65];
  __shared__ float qq[64], kk[64], invq[64], invk[64];
  __shared__ float redm[4][64], reds[4][64];
  const int bid = blockIdx.x;
  if (bid < CCH * BATCH) {
    const int c = bid & (CCH - 1), b = bid >> 9;
    gate_body(x + ((size_t)b * CCH + c) * NPIX, wgt, c, s1, s2, gamma, beta,
              qkv + ((size_t)b * QKV_M + 2 * CCH + c) * NPIX, &Sf[0][0]);
  } else {
    attn_s_body(qkv, temp, P, bid - CCH * BATCH,
                Sf, qq, kk, invq, invk, redm, reds);
  }
}

// ================= fallback standalone kernels (BC < 32 path) ================
__global__ void transpose_f2b(const float* __restrict__ in,
                              unsigned short* __restrict__ out) {
  __shared__ float tile[64][65];
  transpose_body(in + (size_t)blockIdx.z * CCH * NPIX,
                 out + (size_t)blockIdx.z * NPIX * CCH,
                 blockIdx.x * 64, blockIdx.y * 64, tile);
}

__global__ void dw_stats(const float* __restrict__ x, const float* __restrict__ wgt,
                         float* __restrict__ s1, float* __restrict__ s2) {
  __shared__ float plane[NPIX];
  __shared__ float r1[4], r2[4];
  int c = blockIdx.x, b = blockIdx.y;
  stats_body(x + ((size_t)b * CCH + c) * NPIX, wgt, c, s1, s2, plane, r1, r2);
}

__global__ void gate_apply(const float* __restrict__ x, const float* __restrict__ wgt,
                           const float* __restrict__ s1, const float* __restrict__ s2,
                           const float* __restrict__ gamma,
                           const float* __restrict__ beta,
                           unsigned short* __restrict__ qkv) {
  __shared__ float plane[NPIX];
  int c = blockIdx.x, b = blockIdx.y;
  gate_body(x + ((size_t)b * CCH + c) * NPIX, wgt, c, s1, s2, gamma, beta,
            qkv + ((size_t)b * QKV_M + 2 * CCH + c) * NPIX, plane);
}

__launch_bounds__(256)
__global__ void attn_s(const unsigned short* __restrict__ qkv,
                       const float* __restrict__ temp,
                       unsigned short* __restrict__ P) {
  __shared__ float Sf[64][65];
  __shared__ float qq[64], kk[64], invq[64], invk[64];
  __shared__ float redm[4][64], reds[4][64];
  attn_s_body(qkv, temp, P, blockIdx.x, Sf, qq, kk, invq, invk, redm, reds);
}

// ---------------- gemm_bt: C[b][m][n] = sum_k A[m][k]*X[b][n][k] -------------
// 256x256 tile, BK=64, 512 threads = 8 waves (2 M x 4 N), mfma 16x16x32.
// Frozen at its round-5 best (72.3us): schedule class exhausted at K=512.
template <bool OUT_F32>
__launch_bounds__(512, 2)
__global__ void gemm_bt(const unsigned short* __restrict__ A,
                        const unsigned short* __restrict__ X,
                        void* __restrict__ Cout,
                        const float* __restrict__ bias,
                        int M, int N, int K) {
  __shared__ __align__(16) unsigned short As[2][256 * 64];
  __shared__ __align__(16) unsigned short Bs[2][256 * 64];
  const int b  = blockIdx.z;
  const int m0 = blockIdx.y * 256;
  const int n0 = blockIdx.x * 256;
  const unsigned short* Xb = X + (size_t)b * N * K;
  const int tid  = threadIdx.x;
  const int lane = tid & 63;
  const int wave = tid >> 6;        // 0..7
  const int wm = wave >> 2;
  const int wn = wave & 3;
  const int quad = lane >> 4, l16 = lane & 15;

  f32x4 acc[8][4];
  const f32x4 zero = {0.f, 0.f, 0.f, 0.f};
#pragma unroll
  for (int i = 0; i < 8; i++)
#pragma unroll
    for (int j = 0; j < 4; j++) acc[i][j] = zero;

  const int r8  = lane >> 3;
  const int swk = ((lane & 7) ^ r8) * 8;
  const unsigned short* Ag = A  + (size_t)(m0 + wave * 32 + r8) * K + swk;
  const unsigned short* Xg = Xb + (size_t)(n0 + wave * 32 + r8) * K + swk;

  const int NT = K >> 6;

  auto stage = [&](int kt, int bsel) {
    unsigned short* Al = &As[bsel][wave * 32 * 64];
    unsigned short* Bl = &Bs[bsel][wave * 32 * 64];
    const unsigned short* Agk = Ag + kt * 64;
    const unsigned short* Xgk = Xg + kt * 64;
#pragma unroll
    for (int i = 0; i < 4; ++i) {
      gl_lds16(Agk + (size_t)i * 8 * K, Al + i * 8 * 64);
      gl_lds16(Xgk + (size_t)i * 8 * K, Bl + i * 8 * 64);
    }
  };

  stage(0, 0);
  if (NT > 1) stage(1, 1);
  asm volatile("s_waitcnt vmcnt(8)" ::: "memory");
  __builtin_amdgcn_s_barrier();

  for (int t = 0; t < NT; ++t) {
    const int cur = t & 1;
    const unsigned short* Asl = As[cur];
    const unsigned short* Bsl = Bs[cur];

    {
      bf16x8 a0[8], b0[4];
      const int ch0 = ((0 * 4 + quad) ^ (l16 & 7)) * 8;
#pragma unroll
      for (int ii = 0; ii < 8; ++ii)
        a0[ii] = *(const bf16x8*)&Asl[(wm * 128 + ii * 16 + l16) * 64 + ch0];
#pragma unroll
      for (int jj = 0; jj < 4; ++jj)
        b0[jj] = *(const bf16x8*)&Bsl[(wn * 64 + jj * 16 + l16) * 64 + ch0];

      bf16x8 a1[8], b1[4];
      const int ch1 = ((1 * 4 + quad) ^ (l16 & 7)) * 8;
#pragma unroll
      for (int ii = 0; ii < 8; ++ii)
        a1[ii] = *(const bf16x8*)&Asl[(wm * 128 + ii * 16 + l16) * 64 + ch1];
#pragma unroll
      for (int jj = 0; jj < 4; ++jj)
        b1[jj] = *(const bf16x8*)&Bsl[(wn * 64 + jj * 16 + l16) * 64 + ch1];

#pragma unroll
      for (int ii = 0; ii < 8; ++ii)
#pragma unroll
        for (int jj = 0; jj < 4; ++jj)
          acc[ii][jj] = __builtin_amdgcn_mfma_f32_16x16x32_bf16(
              a0[ii], b0[jj], acc[ii][jj], 0, 0, 0);
#pragma unroll
      for (int ii = 0; ii < 8; ++ii)
#pragma unroll
        for (int jj = 0; jj < 4; ++jj)
          acc[ii][jj] = __builtin_amdgcn_mfma_f32_16x16x32_bf16(
              a1[ii], b1[jj], acc[ii][jj], 0, 0, 0);
    }

    __builtin_amdgcn_s_barrier();
    if (t + 2 < NT) {
      stage(t + 2, cur);
      asm volatile("s_waitcnt vmcnt(8)" ::: "memory");
    } else if (t + 1 < NT) {
      asm volatile("s_waitcnt vmcnt(0)" ::: "memory");
    }
    __builtin_amdgcn_s_barrier();
  }

  // C/D layout: row = quad*4+reg, col = l16
#pragma unroll
  for (int i = 0; i < 8; ++i) {
#pragma unroll
    for (int r = 0; r < 4; ++r) {
      const int gm = m0 + wm * 128 + i * 16 + quad * 4 + r;
      if constexpr (OUT_F32) {
        const float bv = bias[gm];
        float* Co = (float*)Cout + (size_t)b * M * N + (size_t)gm * N +
                    n0 + wn * 64 + l16;
#pragma unroll
        for (int j = 0; j < 4; ++j) Co[j * 16] = acc[i][j][r] + bv;
      } else {
        unsigned short* Co = (unsigned short*)Cout + (size_t)b * M * N +
                             (size_t)gm * N + n0 + wn * 64 + l16;
#pragma unroll
        for (int j = 0; j < 4; ++j) Co[j * 16] = f2bf(acc[i][j][r]);
      }
    }
  }
}

// ---------------- attn_o: O^T[n][d] = sum_e V^T[n][e] P[d][e] ----------------
__launch_bounds__(256)
__global__ void attn_o(const unsigned short* __restrict__ qkv,
                       const unsigned short* __restrict__ P,
                       unsigned short* __restrict__ aoT) {
  int blk = blockIdx.x;
  int nc = blk & 7, bh = blk >> 3;
  int b = bh >> 3, h = bh & 7;
  const unsigned short* V = qkv + ((size_t)b * QKV_M + 2 * CCH + h * 64) * NPIX;
  unsigned short* Ob = aoT + (size_t)b * NPIX * CCH + h * 64;
  int tid = threadIdx.x, lane = tid & 63, wave = tid >> 6;
  int quad = lane >> 4, l16 = lane & 15;

  __shared__ __align__(16) unsigned short Vt[4][16][72];
  __shared__ __align__(16) unsigned short Ot[4][16][72];

  const unsigned short* Pb = P + (size_t)bh * 64 * 64;
  bf16x8 Pf[4][2];
  for (int j = 0; j < 4; j++)
    for (int ks = 0; ks < 2; ks++)
      Pf[j][ks] = *(const bf16x8*)&Pb[(j * 16 + l16) * 64 + ks * 32 + quad * 8];

  f32x4 zero = {0.f, 0.f, 0.f, 0.f};
  int e1 = lane >> 1, noff = (lane & 1) * 8;
  int nbase = nc * 128 + wave * 32;
  int orow = lane >> 3, ocol = (lane & 7) * 8;

  union { uint4 q; unsigned short s[8]; } g0, g1, c0, c1;
  g0.q = *(const uint4*)&V[(size_t)e1 * NPIX + nbase + noff];
  g1.q = *(const uint4*)&V[(size_t)(e1 + 32) * NPIX + nbase + noff];
#pragma unroll
  for (int nt = 0; nt < 2; nt++) {
    int n0 = nbase + nt * 16;
    c0 = g0; c1 = g1;
    if (nt < 1) {
      g0.q = *(const uint4*)&V[(size_t)e1 * NPIX + n0 + 16 + noff];
      g1.q = *(const uint4*)&V[(size_t)(e1 + 32) * NPIX + n0 + 16 + noff];
    }
    for (int jj = 0; jj < 8; jj++) {
      Vt[wave][noff + jj][e1]      = c0.s[jj];
      Vt[wave][noff + jj][e1 + 32] = c1.s[jj];
    }
    bf16x8 Af0 = *(const bf16x8*)&Vt[wave][l16][quad * 8];
    bf16x8 Af1 = *(const bf16x8*)&Vt[wave][l16][32 + quad * 8];
    f32x4 oacc[4];
    for (int j = 0; j < 4; j++) {
      oacc[j] = __builtin_amdgcn_mfma_f32_16x16x32_bf16(Af0, Pf[j][0], zero, 0, 0, 0);
      oacc[j] = __builtin_amdgcn_mfma_f32_16x16x32_bf16(Af1, Pf[j][1], oacc[j], 0, 0, 0);
    }
    for (int j = 0; j < 4; j++)
      for (int r = 0; r < 4; r++)
        Ot[wave][quad * 4 + r][j * 16 + l16] = f2bf(oacc[j][r]);
    uint4 o0 = *(const uint4*)&Ot[wave][orow][ocol];
    uint4 o1 = *(const uint4*)&Ot[wave][orow + 8][ocol];
    *(uint4*)&Ob[(size_t)(n0 + orow) * CCH + ocol] = o0;
    *(uint4*)&Ob[(size_t)(n0 + orow + 8) * CCH + ocol] = o1;
  }
}

// ---------------------------------------------------------------------------
extern "C" void kernel_launch(void* const* d_in, const int* in_sizes, int n_in,
                              void* d_out, int out_size, void* d_ws, size_t ws_size,
                              hipStream_t stream) {
  const float* x     = (const float*)d_in[0];
  const float* Wq    = (const float*)d_in[1];
  const float* Wk    = (const float*)d_in[2];
  const float* Wv    = (const float*)d_in[3];
  const float* dww   = (const float*)d_in[4];
  const float* gamma = (const float*)d_in[5];
  const float* beta  = (const float*)d_in[6];
  const float* temp  = (const float*)d_in[7];
  const float* Wp    = (const float*)d_in[8];
  const float* bp    = (const float*)d_in[9];
  float* out = (float*)d_out;

  char* ws = (char*)d_ws;
  unsigned short* wcat = (unsigned short*)ws;             // [1536,512] bf16
  unsigned short* wpb  = wcat + (size_t)QKV_M * CCH;      // [512,512] bf16
  float* s1 = (float*)(wpb + (size_t)CCH * CCH);
  float* s2 = s1 + CCH;
  unsigned short* Pbuf = (unsigned short*)(s2 + CCH);     // [B*H,64,64] bf16, 2MB
  char* dyn = (char*)(Pbuf + (size_t)BATCH * HEADS * 64 * 64);
  size_t fixed = (size_t)(dyn - ws);
  size_t per_b = ((size_t)NPIX * CCH + (size_t)QKV_M * NPIX) * 2;  // 4 MB/batch
  int BC = BATCH;
  while (BC > 1 && fixed + (size_t)BC * per_b > ws_size) BC >>= 1;
  unsigned short* xT  = (unsigned short*)dyn;                  // [BC,N,C]; reused as aoT
  unsigned short* qkv = xT + (size_t)BC * NPIX * CCH;          // [BC,1536,N]

  prep_w<<<CCH * CCH / 1024, 256, 0, stream>>>(Wq, Wk, Wv, Wp, wcat, wpb, s1, s2);

  if (BC == BATCH) {
    // fused path: 6 dispatches total (round-8 launch-overhead experiment)
    stats_transpose<<<CCH * BATCH + (NPIX / 64) * (CCH / 64) * BATCH, 256, 0,
                      stream>>>(x, dww, s1, s2, xT);
    gemm_bt<false><<<dim3(NPIX / 256, QKV_M / 256, BATCH), 512, 0, stream>>>(
        wcat, xT, qkv, nullptr, QKV_M, NPIX, CCH);
    attn_gate<<<CCH * BATCH + BATCH * HEADS, 256, 0, stream>>>(
        qkv, temp, Pbuf, x, dww, s1, s2, gamma, beta);
    attn_o<<<BATCH * HEADS * 8, 256, 0, stream>>>(qkv, Pbuf, xT);
    gemm_bt<true><<<dim3(NPIX / 256, CCH / 256, BATCH), 512, 0, stream>>>(
        wpb, xT, out, bp, CCH, NPIX, CCH);
  } else {
    dw_stats<<<dim3(CCH, BATCH), 256, 0, stream>>>(x, dww, s1, s2);
    for (int b0 = 0; b0 < BATCH; b0 += BC) {
      const float* xc = x + (size_t)b0 * CCH * NPIX;
      float* outc = out + (size_t)b0 * CCH * NPIX;
      transpose_f2b<<<dim3(NPIX / 64, CCH / 64, BC), 256, 0, stream>>>(xc, xT);
      gemm_bt<false><<<dim3(NPIX / 256, QKV_M / 256, BC), 512, 0, stream>>>(
          wcat, xT, qkv, nullptr, QKV_M, NPIX, CCH);
      attn_s<<<BC * HEADS, 256, 0, stream>>>(qkv, temp, Pbuf);
      gate_apply<<<dim3(CCH, BC), 256, 0, stream>>>(xc, dww, s1, s2, gamma, beta, qkv);
      attn_o<<<BC * HEADS * 8, 256, 0, stream>>>(qkv, Pbuf, xT);
      gemm_bt<true><<<dim3(NPIX / 256, CCH / 256, BC), 512, 0, stream>>>(
          wpb, xT, outc, bp, CCH, NPIX, CCH);
    }
  }
}

// Round 10
// 313.788 us; speedup vs baseline: 1.0947x; 1.0947x over previous
//
#include <hip/hip_runtime.h>
#include <stdint.h>

#define BATCH 32
#define CCH   512
#define NPIX  1024
#define HEADS 8
#define QKV_M 1536   // q rows 0-511, k rows 512-1023, v rows 1024-1535

typedef short bf16x8 __attribute__((ext_vector_type(8)));
typedef float f32x4 __attribute__((ext_vector_type(4)));
typedef unsigned short u16x8 __attribute__((ext_vector_type(8)));

__device__ inline float bf2f(unsigned short u) {
  union { float f; uint32_t i; } t; t.i = ((uint32_t)u) << 16; return t.f;
}
__device__ inline unsigned short f2bf(float f) {
  union { float f; uint32_t u; } t; t.f = f;
  uint32_t u = t.u;
  return (unsigned short)((u + 0x7FFFu + ((u >> 16) & 1u)) >> 16);
}

// async global->LDS, 16B per lane; LDS dest = wave-uniform base + lane*16
__device__ inline void gl_lds16(const unsigned short* g, unsigned short* l) {
  __builtin_amdgcn_global_load_lds(
      (const __attribute__((address_space(1))) uint32_t*)g,
      (__attribute__((address_space(3))) uint32_t*)l, 16, 0, 0);
}

// ---------------- prep_w: weights fp32->bf16 AND zero s1/s2 ------------------
__global__ void prep_w(const float* __restrict__ Wq, const float* __restrict__ Wk,
                       const float* __restrict__ Wv, const float* __restrict__ Wp,
                       unsigned short* __restrict__ wcat,
                       unsigned short* __restrict__ wpb,
                       float* __restrict__ s1, float* __restrict__ s2) {
  if (blockIdx.x == 0) {
    const f32x4 z4 = {0.f, 0.f, 0.f, 0.f};
    if (threadIdx.x < 128) ((f32x4*)s1)[threadIdx.x] = z4;
    else ((f32x4*)s2)[threadIdx.x - 128] = z4;
  }
  int i = (blockIdx.x * 256 + threadIdx.x) * 4;   // over CCH*CCH = 262144
  union { ushort4 u4; unsigned short s[4]; } o;
  f32x4 a;
  a = *(const f32x4*)&Wq[i];
  for (int j = 0; j < 4; j++) o.s[j] = f2bf(a[j]);
  *(ushort4*)&wcat[i] = o.u4;
  a = *(const f32x4*)&Wk[i];
  for (int j = 0; j < 4; j++) o.s[j] = f2bf(a[j]);
  *(ushort4*)&wcat[CCH * CCH + i] = o.u4;
  a = *(const f32x4*)&Wv[i];
  for (int j = 0; j < 4; j++) o.s[j] = f2bf(a[j]);
  *(ushort4*)&wcat[2 * CCH * CCH + i] = o.u4;
  a = *(const f32x4*)&Wp[i];
  for (int j = 0; j < 4; j++) o.s[j] = f2bf(a[j]);
  *(ushort4*)&wpb[i] = o.u4;
}

// ---------------- transpose fp32 [b,C,N] -> bf16 [b,N,C] ---------------------
__global__ void transpose_f2b(const float* __restrict__ in,
                              unsigned short* __restrict__ out) {
  __shared__ float tile[64][65];
  const int b  = blockIdx.z;
  const int p0 = blockIdx.x * 64;   // pixel base
  const int c0 = blockIdx.y * 64;   // channel base
  const float* inb = in + (size_t)b * CCH * NPIX;
  unsigned short* outb = out + (size_t)b * NPIX * CCH;
  const int t = threadIdx.x;
  const int cr = t >> 2, tl = t & 3;
#pragma unroll
  for (int j = 0; j < 4; ++j) {
    const int off = j * 16 + tl * 4;
    f32x4 v = *(const f32x4*)&inb[(size_t)(c0 + cr) * NPIX + p0 + off];
    tile[cr][off + 0] = v[0];
    tile[cr][off + 1] = v[1];
    tile[cr][off + 2] = v[2];
    tile[cr][off + 3] = v[3];
  }
  __syncthreads();
  const int pr = t >> 3, cc = (t & 7) * 8;
#pragma unroll
  for (int pass = 0; pass < 2; ++pass) {
    const int p = pr + pass * 32;
    union { u16x8 v; unsigned short s[8]; } o;
#pragma unroll
    for (int j = 0; j < 8; ++j) o.s[j] = f2bf(tile[cc + j][p]);
    *(u16x8*)&outb[(size_t)(p0 + p) * CCH + c0 + cc] = o.v;
  }
}

// ---------------- gemm_bt: C[b][m][n] = sum_k A[m][k]*X[b][n][k] -------------
// 256x256 tile, BK=64, 512 threads = 8 waves (2 M x 4 N), mfma 16x16x32.
// Frozen at its round-5 best (72.3us): schedule class exhausted at K=512.
template <bool OUT_F32>
__launch_bounds__(512, 2)
__global__ void gemm_bt(const unsigned short* __restrict__ A,
                        const unsigned short* __restrict__ X,
                        void* __restrict__ Cout,
                        const float* __restrict__ bias,
                        int M, int N, int K) {
  __shared__ __align__(16) unsigned short As[2][256 * 64];
  __shared__ __align__(16) unsigned short Bs[2][256 * 64];
  const int b  = blockIdx.z;
  const int m0 = blockIdx.y * 256;
  const int n0 = blockIdx.x * 256;
  const unsigned short* Xb = X + (size_t)b * N * K;
  const int tid  = threadIdx.x;
  const int lane = tid & 63;
  const int wave = tid >> 6;        // 0..7
  const int wm = wave >> 2;
  const int wn = wave & 3;
  const int quad = lane >> 4, l16 = lane & 15;

  f32x4 acc[8][4];
  const f32x4 zero = {0.f, 0.f, 0.f, 0.f};
#pragma unroll
  for (int i = 0; i < 8; i++)
#pragma unroll
    for (int j = 0; j < 4; j++) acc[i][j] = zero;

  const int r8  = lane >> 3;
  const int swk = ((lane & 7) ^ r8) * 8;
  const unsigned short* Ag = A  + (size_t)(m0 + wave * 32 + r8) * K + swk;
  const unsigned short* Xg = Xb + (size_t)(n0 + wave * 32 + r8) * K + swk;

  const int NT = K >> 6;

  auto stage = [&](int kt, int bsel) {
    unsigned short* Al = &As[bsel][wave * 32 * 64];
    unsigned short* Bl = &Bs[bsel][wave * 32 * 64];
    const unsigned short* Agk = Ag + kt * 64;
    const unsigned short* Xgk = Xg + kt * 64;
#pragma unroll
    for (int i = 0; i < 4; ++i) {
      gl_lds16(Agk + (size_t)i * 8 * K, Al + i * 8 * 64);
      gl_lds16(Xgk + (size_t)i * 8 * K, Bl + i * 8 * 64);
    }
  };

  stage(0, 0);
  if (NT > 1) stage(1, 1);
  asm volatile("s_waitcnt vmcnt(8)" ::: "memory");
  __builtin_amdgcn_s_barrier();

  for (int t = 0; t < NT; ++t) {
    const int cur = t & 1;
    const unsigned short* Asl = As[cur];
    const unsigned short* Bsl = Bs[cur];

    {
      bf16x8 a0[8], b0[4];
      const int ch0 = ((0 * 4 + quad) ^ (l16 & 7)) * 8;
#pragma unroll
      for (int ii = 0; ii < 8; ++ii)
        a0[ii] = *(const bf16x8*)&Asl[(wm * 128 + ii * 16 + l16) * 64 + ch0];
#pragma unroll
      for (int jj = 0; jj < 4; ++jj)
        b0[jj] = *(const bf16x8*)&Bsl[(wn * 64 + jj * 16 + l16) * 64 + ch0];

      bf16x8 a1[8], b1[4];
      const int ch1 = ((1 * 4 + quad) ^ (l16 & 7)) * 8;
#pragma unroll
      for (int ii = 0; ii < 8; ++ii)
        a1[ii] = *(const bf16x8*)&Asl[(wm * 128 + ii * 16 + l16) * 64 + ch1];
#pragma unroll
      for (int jj = 0; jj < 4; ++jj)
        b1[jj] = *(const bf16x8*)&Bsl[(wn * 64 + jj * 16 + l16) * 64 + ch1];

#pragma unroll
      for (int ii = 0; ii < 8; ++ii)
#pragma unroll
        for (int jj = 0; jj < 4; ++jj)
          acc[ii][jj] = __builtin_amdgcn_mfma_f32_16x16x32_bf16(
              a0[ii], b0[jj], acc[ii][jj], 0, 0, 0);
#pragma unroll
      for (int ii = 0; ii < 8; ++ii)
#pragma unroll
        for (int jj = 0; jj < 4; ++jj)
          acc[ii][jj] = __builtin_amdgcn_mfma_f32_16x16x32_bf16(
              a1[ii], b1[jj], acc[ii][jj], 0, 0, 0);
    }

    __builtin_amdgcn_s_barrier();
    if (t + 2 < NT) {
      stage(t + 2, cur);
      asm volatile("s_waitcnt vmcnt(8)" ::: "memory");
    } else if (t + 1 < NT) {
      asm volatile("s_waitcnt vmcnt(0)" ::: "memory");
    }
    __builtin_amdgcn_s_barrier();
  }

  // C/D layout: row = quad*4+reg, col = l16
#pragma unroll
  for (int i = 0; i < 8; ++i) {
#pragma unroll
    for (int r = 0; r < 4; ++r) {
      const int gm = m0 + wm * 128 + i * 16 + quad * 4 + r;
      if constexpr (OUT_F32) {
        const float bv = bias[gm];
        float* Co = (float*)Cout + (size_t)b * M * N + (size_t)gm * N +
                    n0 + wn * 64 + l16;
#pragma unroll
        for (int j = 0; j < 4; ++j) Co[j * 16] = acc[i][j][r] + bv;
      } else {
        unsigned short* Co = (unsigned short*)Cout + (size_t)b * M * N +
                             (size_t)gm * N + n0 + wn * 64 + l16;
#pragma unroll
        for (int j = 0; j < 4; ++j) Co[j * 16] = f2bf(acc[i][j][r]);
      }
    }
  }
}

// ---------------- depthwise 3x3 per-channel stats (sum, sumsq) ---------------
// conv-read mapping p = t + pi*256 spans 32 columns/wave -> 2 lanes/bank (free)
__global__ void dw_stats(const float* __restrict__ x,
                         const float* __restrict__ wgt,
                         float* __restrict__ s1, float* __restrict__ s2) {
  int c = blockIdx.x, b = blockIdx.y;
  __shared__ __align__(16) float plane[NPIX];
  const float* xp = x + ((size_t)b * CCH + c) * NPIX;
  *(f32x4*)&plane[threadIdx.x * 4] = *(const f32x4*)&xp[threadIdx.x * 4];
  __syncthreads();
  float w[9];
  for (int i = 0; i < 9; i++) w[i] = wgt[c * 9 + i];
  float a1 = 0.f, a2 = 0.f;
  for (int pi = 0; pi < 4; pi++) {
    int p = threadIdx.x + pi * 256;
    int h = p >> 5, wc = p & 31;
    float v = 0.f;
    for (int dh = -1; dh <= 1; dh++)
      for (int dw = -1; dw <= 1; dw++) {
        int hh = h + dh, ww = wc + dw;
        if (hh >= 0 && hh < 32 && ww >= 0 && ww < 32)
          v += w[(dh + 1) * 3 + dw + 1] * plane[hh * 32 + ww];
      }
    a1 += v; a2 += v * v;
  }
  for (int off = 32; off > 0; off >>= 1) {
    a1 += __shfl_down(a1, off);
    a2 += __shfl_down(a2, off);
  }
  __shared__ float r1[4], r2[4];
  int wv = threadIdx.x >> 6;
  if ((threadIdx.x & 63) == 0) { r1[wv] = a1; r2[wv] = a2; }
  __syncthreads();
  if (threadIdx.x == 0) {
    atomicAdd(&s1[c], r1[0] + r1[1] + r1[2] + r1[3]);
    atomicAdd(&s2[c], r2[0] + r2[1] + r2[2] + r2[3]);
  }
}

// ---------------- gate: v (rows 1024..1535 of qkv) *= SiLU(BN(conv(x))) ------
// Round-10 fix: the round-5 remap (h=t>>3, w0=(t&7)*4) made the conv's LDS
// reads 8 lanes/bank (wave spans only 8 columns of a stride-32 plane) --
// measured 1.38e7 SQ_LDS_BANK_CONFLICT, MfmaUtil-starved 102us fused kernel.
// Fix: pad plane rows to stride 33 -> bank = (h+w)%32 -> <=2 lanes/bank
// (free, m136) while KEEPING the vectorized f32x4 global read + ushort4 rmw.
__global__ void gate_apply(const float* __restrict__ x,
                           const float* __restrict__ wgt,
                           const float* __restrict__ s1, const float* __restrict__ s2,
                           const float* __restrict__ gamma,
                           const float* __restrict__ beta,
                           unsigned short* __restrict__ qkv) {
  int c = blockIdx.x, b = blockIdx.y;
  __shared__ float plane[32 * 33];          // stride-33 padded rows
  const float* xp = x + ((size_t)b * CCH + c) * NPIX;
  const int t = threadIdx.x;
  const int h = t >> 3, w0 = (t & 7) * 4;   // 4 consecutive pixels per thread
  {
    f32x4 v = *(const f32x4*)&xp[t * 4];    // coalesced 16B global read
    float* pr = &plane[h * 33 + w0];        // scalar LDS stores (~2-way, one-time)
    pr[0] = v[0]; pr[1] = v[1]; pr[2] = v[2]; pr[3] = v[3];
  }
  __syncthreads();
  float w[9];
  for (int i = 0; i < 9; i++) w[i] = wgt[c * 9 + i];
  const float invn = 1.f / 32768.f;
  float mean = s1[c] * invn;
  float var = fmaxf(s2[c] * invn - mean * mean, 0.f);
  float rstd = rsqrtf(var + 1e-5f);
  float ga = gamma[c], be = beta[c];

  unsigned short* vp = qkv + ((size_t)b * QKV_M + 2 * CCH + c) * NPIX + h * 32 + w0;
  union { ushort4 q; unsigned short s[4]; } vv;
  vv.q = *(const ushort4*)vp;
#pragma unroll
  for (int i = 0; i < 4; ++i) {
    const int wc = w0 + i;
    float val = 0.f;
    for (int dh = -1; dh <= 1; dh++)
      for (int dw = -1; dw <= 1; dw++) {
        int hh = h + dh, ww = wc + dw;
        if (hh >= 0 && hh < 32 && ww >= 0 && ww < 32)
          val += w[(dh + 1) * 3 + dw + 1] * plane[hh * 33 + ww];
      }
    float g = (val - mean) * rstd * ga + be;
    float sg = g / (1.f + __expf(-g));      // SiLU
    vv.s[i] = f2bf(bf2f(vv.s[i]) * sg);
  }
  *(ushort4*)vp = vv.q;
}

// ---------------- attn_s: S=QK^T (+ fused l2norm via QQ^T/KK^T diag),
//                  softmax -> P [bh][64][64] bf16 -------------------------------
__launch_bounds__(256)
__global__ void attn_s(const unsigned short* __restrict__ qkv,
                       const float* __restrict__ temp,
                       unsigned short* __restrict__ P) {
  int bh = blockIdx.x;
  int b = bh >> 3, h = bh & 7;
  const unsigned short* Q = qkv + ((size_t)b * QKV_M + h * 64) * NPIX;
  const unsigned short* K = Q + (size_t)CCH * NPIX;
  int tid = threadIdx.x, lane = tid & 63, wave = tid >> 6;
  int quad = lane >> 4, l16 = lane & 15;

  __shared__ __align__(16) float Sf[64][65];
  __shared__ float qq[64], kk[64], invq[64], invk[64];
  __shared__ float redm[4][64], reds[4][64];

  f32x4 zero = {0.f, 0.f, 0.f, 0.f};
  f32x4 acc[4], accQ = zero, accK = zero;
  for (int j = 0; j < 4; j++) acc[j] = zero;
  for (int n0 = 0; n0 < NPIX; n0 += 32) {
    bf16x8 a  = *(const bf16x8*)&Q[(size_t)(wave * 16 + l16) * NPIX + n0 + quad * 8];
    bf16x8 ak = *(const bf16x8*)&K[(size_t)(wave * 16 + l16) * NPIX + n0 + quad * 8];
    accQ = __builtin_amdgcn_mfma_f32_16x16x32_bf16(a, a, accQ, 0, 0, 0);
    accK = __builtin_amdgcn_mfma_f32_16x16x32_bf16(ak, ak, accK, 0, 0, 0);
    for (int j = 0; j < 4; j++) {
      bf16x8 bb = *(const bf16x8*)&K[(size_t)(j * 16 + l16) * NPIX + n0 + quad * 8];
      acc[j] = __builtin_amdgcn_mfma_f32_16x16x32_bf16(a, bb, acc[j], 0, 0, 0);
    }
  }
  for (int j = 0; j < 4; j++)
    for (int r = 0; r < 4; r++)
      Sf[wave * 16 + quad * 4 + r][j * 16 + l16] = acc[j][r];
  for (int r = 0; r < 4; r++)
    if (l16 == quad * 4 + r) {
      qq[wave * 16 + l16] = accQ[r];
      kk[wave * 16 + l16] = accK[r];
    }
  __syncthreads();
  if (tid < 64) invq[tid] = 1.f / fmaxf(sqrtf(qq[tid]), 1e-12f);
  else if (tid < 128) invk[tid - 64] = 1.f / fmaxf(sqrtf(kk[tid - 64]), 1e-12f);
  __syncthreads();

  int row = tid & 63, seg = tid >> 6;
  float fq = temp[h] * invq[row];
  float v[16], pm = -1e30f;
  for (int i = 0; i < 16; i++) {
    v[i] = Sf[row][seg * 16 + i] * fq * invk[seg * 16 + i];
    pm = fmaxf(pm, v[i]);
  }
  redm[seg][row] = pm;
  __syncthreads();
  float m = fmaxf(fmaxf(redm[0][row], redm[1][row]),
                  fmaxf(redm[2][row], redm[3][row]));
  float ps = 0.f;
  for (int i = 0; i < 16; i++) { v[i] = __expf(v[i] - m); ps += v[i]; }
  reds[seg][row] = ps;
  __syncthreads();
  float inv = 1.f / (reds[0][row] + reds[1][row] + reds[2][row] + reds[3][row]);
  union { uint4 q4[2]; unsigned short s[16]; } u;
  for (int i = 0; i < 16; i++) u.s[i] = f2bf(v[i] * inv);
  unsigned short* Pp = P + ((size_t)bh * 64 + row) * 64 + seg * 16;
  *(uint4*)&Pp[0] = u.q4[0];
  *(uint4*)&Pp[8] = u.q4[1];
}

// ---------------- attn_o: O^T[n][d] = sum_e V^T[n][e] P[d][e] ----------------
__launch_bounds__(256)
__global__ void attn_o(const unsigned short* __restrict__ qkv,
                       const unsigned short* __restrict__ P,
                       unsigned short* __restrict__ aoT) {
  int blk = blockIdx.x;
  int nc = blk & 7, bh = blk >> 3;
  int b = bh >> 3, h = bh & 7;
  const unsigned short* V = qkv + ((size_t)b * QKV_M + 2 * CCH + h * 64) * NPIX;
  unsigned short* Ob = aoT + (size_t)b * NPIX * CCH + h * 64;
  int tid = threadIdx.x, lane = tid & 63, wave = tid >> 6;
  int quad = lane >> 4, l16 = lane & 15;

  __shared__ __align__(16) unsigned short Vt[4][16][72];
  __shared__ __align__(16) unsigned short Ot[4][16][72];

  const unsigned short* Pb = P + (size_t)bh * 64 * 64;
  bf16x8 Pf[4][2];
  for (int j = 0; j < 4; j++)
    for (int ks = 0; ks < 2; ks++)
      Pf[j][ks] = *(const bf16x8*)&Pb[(j * 16 + l16) * 64 + ks * 32 + quad * 8];

  f32x4 zero = {0.f, 0.f, 0.f, 0.f};
  int e1 = lane >> 1, noff = (lane & 1) * 8;
  int nbase = nc * 128 + wave * 32;
  int orow = lane >> 3, ocol = (lane & 7) * 8;

  union { uint4 q; unsigned short s[8]; } g0, g1, c0, c1;
  g0.q = *(const uint4*)&V[(size_t)e1 * NPIX + nbase + noff];
  g1.q = *(const uint4*)&V[(size_t)(e1 + 32) * NPIX + nbase + noff];
#pragma unroll
  for (int nt = 0; nt < 2; nt++) {
    int n0 = nbase + nt * 16;
    c0 = g0; c1 = g1;
    if (nt < 1) {
      g0.q = *(const uint4*)&V[(size_t)e1 * NPIX + n0 + 16 + noff];
      g1.q = *(const uint4*)&V[(size_t)(e1 + 32) * NPIX + n0 + 16 + noff];
    }
    for (int jj = 0; jj < 8; jj++) {
      Vt[wave][noff + jj][e1]      = c0.s[jj];
      Vt[wave][noff + jj][e1 + 32] = c1.s[jj];
    }
    bf16x8 Af0 = *(const bf16x8*)&Vt[wave][l16][quad * 8];
    bf16x8 Af1 = *(const bf16x8*)&Vt[wave][l16][32 + quad * 8];
    f32x4 oacc[4];
    for (int j = 0; j < 4; j++) {
      oacc[j] = __builtin_amdgcn_mfma_f32_16x16x32_bf16(Af0, Pf[j][0], zero, 0, 0, 0);
      oacc[j] = __builtin_amdgcn_mfma_f32_16x16x32_bf16(Af1, Pf[j][1], oacc[j], 0, 0, 0);
    }
    for (int j = 0; j < 4; j++)
      for (int r = 0; r < 4; r++)
        Ot[wave][quad * 4 + r][j * 16 + l16] = f2bf(oacc[j][r]);
    uint4 o0 = *(const uint4*)&Ot[wave][orow][ocol];
    uint4 o1 = *(const uint4*)&Ot[wave][orow + 8][ocol];
    *(uint4*)&Ob[(size_t)(n0 + orow) * CCH + ocol] = o0;
    *(uint4*)&Ob[(size_t)(n0 + orow + 8) * CCH + ocol] = o1;
  }
}

// ---------------------------------------------------------------------------
extern "C" void kernel_launch(void* const* d_in, const int* in_sizes, int n_in,
                              void* d_out, int out_size, void* d_ws, size_t ws_size,
                              hipStream_t stream) {
  const float* x     = (const float*)d_in[0];
  const float* Wq    = (const float*)d_in[1];
  const float* Wk    = (const float*)d_in[2];
  const float* Wv    = (const float*)d_in[3];
  const float* dww   = (const float*)d_in[4];
  const float* gamma = (const float*)d_in[5];
  const float* beta  = (const float*)d_in[6];
  const float* temp  = (const float*)d_in[7];
  const float* Wp    = (const float*)d_in[8];
  const float* bp    = (const float*)d_in[9];
  float* out = (float*)d_out;

  char* ws = (char*)d_ws;
  unsigned short* wcat = (unsigned short*)ws;             // [1536,512] bf16
  unsigned short* wpb  = wcat + (size_t)QKV_M * CCH;      // [512,512] bf16
  float* s1 = (float*)(wpb + (size_t)CCH * CCH);
  float* s2 = s1 + CCH;
  unsigned short* Pbuf = (unsigned short*)(s2 + CCH);     // [B*H,64,64] bf16, 2MB
  char* dyn = (char*)(Pbuf + (size_t)BATCH * HEADS * 64 * 64);
  size_t fixed = (size_t)(dyn - ws);
  size_t per_b = ((size_t)NPIX * CCH + (size_t)QKV_M * NPIX) * 2;  // 4 MB/batch
  int BC = BATCH;
  while (BC > 1 && fixed + (size_t)BC * per_b > ws_size) BC >>= 1;
  unsigned short* xT  = (unsigned short*)dyn;                  // [BC,N,C]; reused as aoT
  unsigned short* qkv = xT + (size_t)BC * NPIX * CCH;          // [BC,1536,N]

  prep_w<<<CCH * CCH / 1024, 256, 0, stream>>>(Wq, Wk, Wv, Wp, wcat, wpb, s1, s2);
  dw_stats<<<dim3(CCH, BATCH), 256, 0, stream>>>(x, dww, s1, s2);

  for (int b0 = 0; b0 < BATCH; b0 += BC) {
    const float* xc = x + (size_t)b0 * CCH * NPIX;
    float* outc = out + (size_t)b0 * CCH * NPIX;
    transpose_f2b<<<dim3(NPIX / 64, CCH / 64, BC), 256, 0, stream>>>(xc, xT);
    gemm_bt<false><<<dim3(NPIX / 256, QKV_M / 256, BC), 512, 0, stream>>>(
        wcat, xT, qkv, nullptr, QKV_M, NPIX, CCH);
    attn_s<<<BC * HEADS, 256, 0, stream>>>(qkv, temp, Pbuf);
    gate_apply<<<dim3(CCH, BC), 256, 0, stream>>>(xc, dww, s1, s2, gamma, beta, qkv);
    attn_o<<<BC * HEADS * 8, 256, 0, stream>>>(qkv, Pbuf, xT);
    gemm_bt<true><<<dim3(NPIX / 256, CCH / 256, BC), 512, 0, stream>>>(
        wpb, xT, outc, bp, CCH, NPIX, CCH);
  }
}

// Round 11
// 311.845 us; speedup vs baseline: 1.1015x; 1.0062x over previous
//
#include <hip/hip_runtime.h>
#include <stdint.h>

#define BATCH 32
#define CCH   512
#define NPIX  1024
#define HEADS 8
#define QKV_M 1536   // q rows 0-511, k rows 512-1023, v rows 1024-1535

typedef short bf16x8 __attribute__((ext_vector_type(8)));
typedef float f32x4 __attribute__((ext_vector_type(4)));
typedef unsigned short u16x8 __attribute__((ext_vector_type(8)));

__device__ inline float bf2f(unsigned short u) {
  union { float f; uint32_t i; } t; t.i = ((uint32_t)u) << 16; return t.f;
}
__device__ inline unsigned short f2bf(float f) {
  union { float f; uint32_t u; } t; t.f = f;
  uint32_t u = t.u;
  return (unsigned short)((u + 0x7FFFu + ((u >> 16) & 1u)) >> 16);
}

// async global->LDS, 16B per lane; LDS dest = wave-uniform base + lane*16
__device__ inline void gl_lds16(const unsigned short* g, unsigned short* l) {
  __builtin_amdgcn_global_load_lds(
      (const __attribute__((address_space(1))) uint32_t*)g,
      (__attribute__((address_space(3))) uint32_t*)l, 16, 0, 0);
}

// ---------------- prep_w: weights fp32->bf16 AND zero s1/s2 ------------------
__global__ void prep_w(const float* __restrict__ Wq, const float* __restrict__ Wk,
                       const float* __restrict__ Wv, const float* __restrict__ Wp,
                       unsigned short* __restrict__ wcat,
                       unsigned short* __restrict__ wpb,
                       float* __restrict__ s1, float* __restrict__ s2) {
  if (blockIdx.x == 0) {
    const f32x4 z4 = {0.f, 0.f, 0.f, 0.f};
    if (threadIdx.x < 128) ((f32x4*)s1)[threadIdx.x] = z4;
    else ((f32x4*)s2)[threadIdx.x - 128] = z4;
  }
  int i = (blockIdx.x * 256 + threadIdx.x) * 4;   // over CCH*CCH = 262144
  union { ushort4 u4; unsigned short s[4]; } o;
  f32x4 a;
  a = *(const f32x4*)&Wq[i];
  for (int j = 0; j < 4; j++) o.s[j] = f2bf(a[j]);
  *(ushort4*)&wcat[i] = o.u4;
  a = *(const f32x4*)&Wk[i];
  for (int j = 0; j < 4; j++) o.s[j] = f2bf(a[j]);
  *(ushort4*)&wcat[CCH * CCH + i] = o.u4;
  a = *(const f32x4*)&Wv[i];
  for (int j = 0; j < 4; j++) o.s[j] = f2bf(a[j]);
  *(ushort4*)&wcat[2 * CCH * CCH + i] = o.u4;
  a = *(const f32x4*)&Wp[i];
  for (int j = 0; j < 4; j++) o.s[j] = f2bf(a[j]);
  *(ushort4*)&wpb[i] = o.u4;
}

// ---------------- transpose fp32 [b,C,N] -> bf16 [b,N,C] ---------------------
__global__ void transpose_f2b(const float* __restrict__ in,
                              unsigned short* __restrict__ out) {
  __shared__ float tile[64][65];
  const int b  = blockIdx.z;
  const int p0 = blockIdx.x * 64;   // pixel base
  const int c0 = blockIdx.y * 64;   // channel base
  const float* inb = in + (size_t)b * CCH * NPIX;
  unsigned short* outb = out + (size_t)b * NPIX * CCH;
  const int t = threadIdx.x;
  const int cr = t >> 2, tl = t & 3;
#pragma unroll
  for (int j = 0; j < 4; ++j) {
    const int off = j * 16 + tl * 4;
    f32x4 v = *(const f32x4*)&inb[(size_t)(c0 + cr) * NPIX + p0 + off];
    tile[cr][off + 0] = v[0];
    tile[cr][off + 1] = v[1];
    tile[cr][off + 2] = v[2];
    tile[cr][off + 3] = v[3];
  }
  __syncthreads();
  const int pr = t >> 3, cc = (t & 7) * 8;
#pragma unroll
  for (int pass = 0; pass < 2; ++pass) {
    const int p = pr + pass * 32;
    union { u16x8 v; unsigned short s[8]; } o;
#pragma unroll
    for (int j = 0; j < 8; ++j) o.s[j] = f2bf(tile[cc + j][p]);
    *(u16x8*)&outb[(size_t)(p0 + p) * CCH + c0 + cc] = o.v;
  }
}

// ---------------- gemm_bt128: bf16-out GEMM, 128x128 tile --------------------
// Round-11 experiment: gemm<false> is latency/barrier-bound at 1 block/CU
// (128KB LDS). Intra-block schedules failed 3x (rounds 1-5, MfmaUtil pinned
// 23-28%). The untested mechanism is INTER-BLOCK TLP (m114: co-resident
// blocks' MFMA/stall phases overlap fully): 128^2 tile -> 64KB LDS dbuf ->
// 2 blocks/CU. 256 thr = 4 waves (2x2); per-wave staging load count (8/tile)
// identical to 256^2 version, so the counted-vmcnt(8) skeleton ports as-is.
// gemm<true> stays 256^2 (fp32-write-floor-bound) as the A/B control.
__launch_bounds__(256, 2)
__global__ void gemm_bt128(const unsigned short* __restrict__ A,
                           const unsigned short* __restrict__ X,
                           unsigned short* __restrict__ Cout,
                           int M, int N, int K) {
  __shared__ __align__(16) unsigned short As[2][128 * 64];
  __shared__ __align__(16) unsigned short Bs[2][128 * 64];
  const int b  = blockIdx.z;
  const int m0 = blockIdx.y * 128;
  const int n0 = blockIdx.x * 128;
  const unsigned short* Xb = X + (size_t)b * N * K;
  const int tid  = threadIdx.x;
  const int lane = tid & 63;
  const int wave = tid >> 6;        // 0..3
  const int wm = wave >> 1;         // 0..1 (M half: 64 rows)
  const int wn = wave & 1;          // 0..1 (N half: 64 cols)
  const int quad = lane >> 4, l16 = lane & 15;

  f32x4 acc[4][4];
  const f32x4 zero = {0.f, 0.f, 0.f, 0.f};
#pragma unroll
  for (int i = 0; i < 4; i++)
#pragma unroll
    for (int j = 0; j < 4; j++) acc[i][j] = zero;

  // staging: wave w covers rows [w*32, w*32+32), 4 loads of 8 rows per matrix
  // lane -> row += lane>>3; fetched k-chunk = (lane&7)^(lane>>3) (XOR swizzle)
  const int r8  = lane >> 3;
  const int swk = ((lane & 7) ^ r8) * 8;
  const unsigned short* Ag = A  + (size_t)(m0 + wave * 32 + r8) * K + swk;
  const unsigned short* Xg = Xb + (size_t)(n0 + wave * 32 + r8) * K + swk;

  const int NT = K >> 6;            // K-tiles of 64

  auto stage = [&](int kt, int bsel) {
    unsigned short* Al = &As[bsel][wave * 32 * 64];
    unsigned short* Bl = &Bs[bsel][wave * 32 * 64];
    const unsigned short* Agk = Ag + kt * 64;
    const unsigned short* Xgk = Xg + kt * 64;
#pragma unroll
    for (int i = 0; i < 4; ++i) {
      gl_lds16(Agk + (size_t)i * 8 * K, Al + i * 8 * 64);
      gl_lds16(Xgk + (size_t)i * 8 * K, Bl + i * 8 * 64);
    }
  };

  // prologue: tiles 0,1 in flight (16 loads/wave); vmcnt(8) = tile 0 landed
  stage(0, 0);
  if (NT > 1) stage(1, 1);
  asm volatile("s_waitcnt vmcnt(8)" ::: "memory");
  __builtin_amdgcn_s_barrier();

  for (int t = 0; t < NT; ++t) {
    const int cur = t & 1;
    const unsigned short* Asl = As[cur];
    const unsigned short* Bsl = Bs[cur];

    // unpinned compute region: 16 ds_read_b128 + 32 MFMA (compiler schedules)
    {
      bf16x8 a0[4], b0[4], a1[4], b1[4];
      const int ch0 = ((0 * 4 + quad) ^ (l16 & 7)) * 8;
      const int ch1 = ((1 * 4 + quad) ^ (l16 & 7)) * 8;
#pragma unroll
      for (int ii = 0; ii < 4; ++ii) {
        a0[ii] = *(const bf16x8*)&Asl[(wm * 64 + ii * 16 + l16) * 64 + ch0];
        a1[ii] = *(const bf16x8*)&Asl[(wm * 64 + ii * 16 + l16) * 64 + ch1];
      }
#pragma unroll
      for (int jj = 0; jj < 4; ++jj) {
        b0[jj] = *(const bf16x8*)&Bsl[(wn * 64 + jj * 16 + l16) * 64 + ch0];
        b1[jj] = *(const bf16x8*)&Bsl[(wn * 64 + jj * 16 + l16) * 64 + ch1];
      }
#pragma unroll
      for (int ii = 0; ii < 4; ++ii)
#pragma unroll
        for (int jj = 0; jj < 4; ++jj)
          acc[ii][jj] = __builtin_amdgcn_mfma_f32_16x16x32_bf16(
              a0[ii], b0[jj], acc[ii][jj], 0, 0, 0);
#pragma unroll
      for (int ii = 0; ii < 4; ++ii)
#pragma unroll
        for (int jj = 0; jj < 4; ++jj)
          acc[ii][jj] = __builtin_amdgcn_mfma_f32_16x16x32_bf16(
              a1[ii], b1[jj], acc[ii][jj], 0, 0, 0);
    }

    __builtin_amdgcn_s_barrier();      // all waves consumed buf cur
    if (t + 2 < NT) {
      stage(t + 2, cur);               // overwrite drained buffer
      asm volatile("s_waitcnt vmcnt(8)" ::: "memory");  // tile t+1 landed
    } else if (t + 1 < NT) {
      asm volatile("s_waitcnt vmcnt(0)" ::: "memory");  // final drain
    }
    __builtin_amdgcn_s_barrier();      // publish tile t+1
  }

  // C/D layout: row = quad*4+reg, col = l16
#pragma unroll
  for (int i = 0; i < 4; ++i) {
#pragma unroll
    for (int r = 0; r < 4; ++r) {
      const int gm = m0 + wm * 64 + i * 16 + quad * 4 + r;
      unsigned short* Co = Cout + (size_t)b * M * N + (size_t)gm * N +
                           n0 + wn * 64 + l16;
#pragma unroll
      for (int j = 0; j < 4; ++j) Co[j * 16] = f2bf(acc[i][j][r]);
    }
  }
}

// ---------------- gemm_bt: C[b][m][n] = sum_k A[m][k]*X[b][n][k] -------------
// 256x256 tile, BK=64, 512 threads = 8 waves (2 M x 4 N), mfma 16x16x32.
// Used for the Wp projection (fp32-write-floor-bound at 1 round; control).
template <bool OUT_F32>
__launch_bounds__(512, 2)
__global__ void gemm_bt(const unsigned short* __restrict__ A,
                        const unsigned short* __restrict__ X,
                        void* __restrict__ Cout,
                        const float* __restrict__ bias,
                        int M, int N, int K) {
  __shared__ __align__(16) unsigned short As[2][256 * 64];
  __shared__ __align__(16) unsigned short Bs[2][256 * 64];
  const int b  = blockIdx.z;
  const int m0 = blockIdx.y * 256;
  const int n0 = blockIdx.x * 256;
  const unsigned short* Xb = X + (size_t)b * N * K;
  const int tid  = threadIdx.x;
  const int lane = tid & 63;
  const int wave = tid >> 6;        // 0..7
  const int wm = wave >> 2;
  const int wn = wave & 3;
  const int quad = lane >> 4, l16 = lane & 15;

  f32x4 acc[8][4];
  const f32x4 zero = {0.f, 0.f, 0.f, 0.f};
#pragma unroll
  for (int i = 0; i < 8; i++)
#pragma unroll
    for (int j = 0; j < 4; j++) acc[i][j] = zero;

  const int r8  = lane >> 3;
  const int swk = ((lane & 7) ^ r8) * 8;
  const unsigned short* Ag = A  + (size_t)(m0 + wave * 32 + r8) * K + swk;
  const unsigned short* Xg = Xb + (size_t)(n0 + wave * 32 + r8) * K + swk;

  const int NT = K >> 6;

  auto stage = [&](int kt, int bsel) {
    unsigned short* Al = &As[bsel][wave * 32 * 64];
    unsigned short* Bl = &Bs[bsel][wave * 32 * 64];
    const unsigned short* Agk = Ag + kt * 64;
    const unsigned short* Xgk = Xg + kt * 64;
#pragma unroll
    for (int i = 0; i < 4; ++i) {
      gl_lds16(Agk + (size_t)i * 8 * K, Al + i * 8 * 64);
      gl_lds16(Xgk + (size_t)i * 8 * K, Bl + i * 8 * 64);
    }
  };

  stage(0, 0);
  if (NT > 1) stage(1, 1);
  asm volatile("s_waitcnt vmcnt(8)" ::: "memory");
  __builtin_amdgcn_s_barrier();

  for (int t = 0; t < NT; ++t) {
    const int cur = t & 1;
    const unsigned short* Asl = As[cur];
    const unsigned short* Bsl = Bs[cur];

    {
      bf16x8 a0[8], b0[4];
      const int ch0 = ((0 * 4 + quad) ^ (l16 & 7)) * 8;
#pragma unroll
      for (int ii = 0; ii < 8; ++ii)
        a0[ii] = *(const bf16x8*)&Asl[(wm * 128 + ii * 16 + l16) * 64 + ch0];
#pragma unroll
      for (int jj = 0; jj < 4; ++jj)
        b0[jj] = *(const bf16x8*)&Bsl[(wn * 64 + jj * 16 + l16) * 64 + ch0];

      bf16x8 a1[8], b1[4];
      const int ch1 = ((1 * 4 + quad) ^ (l16 & 7)) * 8;
#pragma unroll
      for (int ii = 0; ii < 8; ++ii)
        a1[ii] = *(const bf16x8*)&Asl[(wm * 128 + ii * 16 + l16) * 64 + ch1];
#pragma unroll
      for (int jj = 0; jj < 4; ++jj)
        b1[jj] = *(const bf16x8*)&Bsl[(wn * 64 + jj * 16 + l16) * 64 + ch1];

#pragma unroll
      for (int ii = 0; ii < 8; ++ii)
#pragma unroll
        for (int jj = 0; jj < 4; ++jj)
          acc[ii][jj] = __builtin_amdgcn_mfma_f32_16x16x32_bf16(
              a0[ii], b0[jj], acc[ii][jj], 0, 0, 0);
#pragma unroll
      for (int ii = 0; ii < 8; ++ii)
#pragma unroll
        for (int jj = 0; jj < 4; ++jj)
          acc[ii][jj] = __builtin_amdgcn_mfma_f32_16x16x32_bf16(
              a1[ii], b1[jj], acc[ii][jj], 0, 0, 0);
    }

    __builtin_amdgcn_s_barrier();
    if (t + 2 < NT) {
      stage(t + 2, cur);
      asm volatile("s_waitcnt vmcnt(8)" ::: "memory");
    } else if (t + 1 < NT) {
      asm volatile("s_waitcnt vmcnt(0)" ::: "memory");
    }
    __builtin_amdgcn_s_barrier();
  }

  // C/D layout: row = quad*4+reg, col = l16
#pragma unroll
  for (int i = 0; i < 8; ++i) {
#pragma unroll
    for (int r = 0; r < 4; ++r) {
      const int gm = m0 + wm * 128 + i * 16 + quad * 4 + r;
      if constexpr (OUT_F32) {
        const float bv = bias[gm];
        float* Co = (float*)Cout + (size_t)b * M * N + (size_t)gm * N +
                    n0 + wn * 64 + l16;
#pragma unroll
        for (int j = 0; j < 4; ++j) Co[j * 16] = acc[i][j][r] + bv;
      } else {
        unsigned short* Co = (unsigned short*)Cout + (size_t)b * M * N +
                             (size_t)gm * N + n0 + wn * 64 + l16;
#pragma unroll
        for (int j = 0; j < 4; ++j) Co[j * 16] = f2bf(acc[i][j][r]);
      }
    }
  }
}

// ---------------- depthwise 3x3 per-channel stats (sum, sumsq) ---------------
__global__ void dw_stats(const float* __restrict__ x,
                         const float* __restrict__ wgt,
                         float* __restrict__ s1, float* __restrict__ s2) {
  int c = blockIdx.x, b = blockIdx.y;
  __shared__ __align__(16) float plane[NPIX];
  const float* xp = x + ((size_t)b * CCH + c) * NPIX;
  *(f32x4*)&plane[threadIdx.x * 4] = *(const f32x4*)&xp[threadIdx.x * 4];
  __syncthreads();
  float w[9];
  for (int i = 0; i < 9; i++) w[i] = wgt[c * 9 + i];
  float a1 = 0.f, a2 = 0.f;
  for (int pi = 0; pi < 4; pi++) {
    int p = threadIdx.x + pi * 256;
    int h = p >> 5, wc = p & 31;
    float v = 0.f;
    for (int dh = -1; dh <= 1; dh++)
      for (int dw = -1; dw <= 1; dw++) {
        int hh = h + dh, ww = wc + dw;
        if (hh >= 0 && hh < 32 && ww >= 0 && ww < 32)
          v += w[(dh + 1) * 3 + dw + 1] * plane[hh * 32 + ww];
      }
    a1 += v; a2 += v * v;
  }
  for (int off = 32; off > 0; off >>= 1) {
    a1 += __shfl_down(a1, off);
    a2 += __shfl_down(a2, off);
  }
  __shared__ float r1[4], r2[4];
  int wv = threadIdx.x >> 6;
  if ((threadIdx.x & 63) == 0) { r1[wv] = a1; r2[wv] = a2; }
  __syncthreads();
  if (threadIdx.x == 0) {
    atomicAdd(&s1[c], r1[0] + r1[1] + r1[2] + r1[3]);
    atomicAdd(&s2[c], r2[0] + r2[1] + r2[2] + r2[3]);
  }
}

// ---------------- gate: v (rows 1024..1535 of qkv) *= SiLU(BN(conv(x))) ------
// stride-33 padded plane: conv reads <=2 lanes/bank (round-10 fix, -9us)
__global__ void gate_apply(const float* __restrict__ x,
                           const float* __restrict__ wgt,
                           const float* __restrict__ s1, const float* __restrict__ s2,
                           const float* __restrict__ gamma,
                           const float* __restrict__ beta,
                           unsigned short* __restrict__ qkv) {
  int c = blockIdx.x, b = blockIdx.y;
  __shared__ float plane[32 * 33];
  const float* xp = x + ((size_t)b * CCH + c) * NPIX;
  const int t = threadIdx.x;
  const int h = t >> 3, w0 = (t & 7) * 4;
  {
    f32x4 v = *(const f32x4*)&xp[t * 4];
    float* pr = &plane[h * 33 + w0];
    pr[0] = v[0]; pr[1] = v[1]; pr[2] = v[2]; pr[3] = v[3];
  }
  __syncthreads();
  float w[9];
  for (int i = 0; i < 9; i++) w[i] = wgt[c * 9 + i];
  const float invn = 1.f / 32768.f;
  float mean = s1[c] * invn;
  float var = fmaxf(s2[c] * invn - mean * mean, 0.f);
  float rstd = rsqrtf(var + 1e-5f);
  float ga = gamma[c], be = beta[c];

  unsigned short* vp = qkv + ((size_t)b * QKV_M + 2 * CCH + c) * NPIX + h * 32 + w0;
  union { ushort4 q; unsigned short s[4]; } vv;
  vv.q = *(const ushort4*)vp;
#pragma unroll
  for (int i = 0; i < 4; ++i) {
    const int wc = w0 + i;
    float val = 0.f;
    for (int dh = -1; dh <= 1; dh++)
      for (int dw = -1; dw <= 1; dw++) {
        int hh = h + dh, ww = wc + dw;
        if (hh >= 0 && hh < 32 && ww >= 0 && ww < 32)
          val += w[(dh + 1) * 3 + dw + 1] * plane[hh * 33 + ww];
      }
    float g = (val - mean) * rstd * ga + be;
    float sg = g / (1.f + __expf(-g));      // SiLU
    vv.s[i] = f2bf(bf2f(vv.s[i]) * sg);
  }
  *(ushort4*)vp = vv.q;
}

// ---------------- attn_s: S=QK^T (+ fused l2norm via QQ^T/KK^T diag),
//                  softmax -> P [bh][64][64] bf16 -------------------------------
__launch_bounds__(256)
__global__ void attn_s(const unsigned short* __restrict__ qkv,
                       const float* __restrict__ temp,
                       unsigned short* __restrict__ P) {
  int bh = blockIdx.x;
  int b = bh >> 3, h = bh & 7;
  const unsigned short* Q = qkv + ((size_t)b * QKV_M + h * 64) * NPIX;
  const unsigned short* K = Q + (size_t)CCH * NPIX;
  int tid = threadIdx.x, lane = tid & 63, wave = tid >> 6;
  int quad = lane >> 4, l16 = lane & 15;

  __shared__ __align__(16) float Sf[64][65];
  __shared__ float qq[64], kk[64], invq[64], invk[64];
  __shared__ float redm[4][64], reds[4][64];

  f32x4 zero = {0.f, 0.f, 0.f, 0.f};
  f32x4 acc[4], accQ = zero, accK = zero;
  for (int j = 0; j < 4; j++) acc[j] = zero;
  for (int n0 = 0; n0 < NPIX; n0 += 32) {
    bf16x8 a  = *(const bf16x8*)&Q[(size_t)(wave * 16 + l16) * NPIX + n0 + quad * 8];
    bf16x8 ak = *(const bf16x8*)&K[(size_t)(wave * 16 + l16) * NPIX + n0 + quad * 8];
    accQ = __builtin_amdgcn_mfma_f32_16x16x32_bf16(a, a, accQ, 0, 0, 0);
    accK = __builtin_amdgcn_mfma_f32_16x16x32_bf16(ak, ak, accK, 0, 0, 0);
    for (int j = 0; j < 4; j++) {
      bf16x8 bb = *(const bf16x8*)&K[(size_t)(j * 16 + l16) * NPIX + n0 + quad * 8];
      acc[j] = __builtin_amdgcn_mfma_f32_16x16x32_bf16(a, bb, acc[j], 0, 0, 0);
    }
  }
  for (int j = 0; j < 4; j++)
    for (int r = 0; r < 4; r++)
      Sf[wave * 16 + quad * 4 + r][j * 16 + l16] = acc[j][r];
  for (int r = 0; r < 4; r++)
    if (l16 == quad * 4 + r) {
      qq[wave * 16 + l16] = accQ[r];
      kk[wave * 16 + l16] = accK[r];
    }
  __syncthreads();
  if (tid < 64) invq[tid] = 1.f / fmaxf(sqrtf(qq[tid]), 1e-12f);
  else if (tid < 128) invk[tid - 64] = 1.f / fmaxf(sqrtf(kk[tid - 64]), 1e-12f);
  __syncthreads();

  int row = tid & 63, seg = tid >> 6;
  float fq = temp[h] * invq[row];
  float v[16], pm = -1e30f;
  for (int i = 0; i < 16; i++) {
    v[i] = Sf[row][seg * 16 + i] * fq * invk[seg * 16 + i];
    pm = fmaxf(pm, v[i]);
  }
  redm[seg][row] = pm;
  __syncthreads();
  float m = fmaxf(fmaxf(redm[0][row], redm[1][row]),
                  fmaxf(redm[2][row], redm[3][row]));
  float ps = 0.f;
  for (int i = 0; i < 16; i++) { v[i] = __expf(v[i] - m); ps += v[i]; }
  reds[seg][row] = ps;
  __syncthreads();
  float inv = 1.f / (reds[0][row] + reds[1][row] + reds[2][row] + reds[3][row]);
  union { uint4 q4[2]; unsigned short s[16]; } u;
  for (int i = 0; i < 16; i++) u.s[i] = f2bf(v[i] * inv);
  unsigned short* Pp = P + ((size_t)bh * 64 + row) * 64 + seg * 16;
  *(uint4*)&Pp[0] = u.q4[0];
  *(uint4*)&Pp[8] = u.q4[1];
}

// ---------------- attn_o: O^T[n][d] = sum_e V^T[n][e] P[d][e] ----------------
__launch_bounds__(256)
__global__ void attn_o(const unsigned short* __restrict__ qkv,
                       const unsigned short* __restrict__ P,
                       unsigned short* __restrict__ aoT) {
  int blk = blockIdx.x;
  int nc = blk & 7, bh = blk >> 3;
  int b = bh >> 3, h = bh & 7;
  const unsigned short* V = qkv + ((size_t)b * QKV_M + 2 * CCH + h * 64) * NPIX;
  unsigned short* Ob = aoT + (size_t)b * NPIX * CCH + h * 64;
  int tid = threadIdx.x, lane = tid & 63, wave = tid >> 6;
  int quad = lane >> 4, l16 = lane & 15;

  __shared__ __align__(16) unsigned short Vt[4][16][72];
  __shared__ __align__(16) unsigned short Ot[4][16][72];

  const unsigned short* Pb = P + (size_t)bh * 64 * 64;
  bf16x8 Pf[4][2];
  for (int j = 0; j < 4; j++)
    for (int ks = 0; ks < 2; ks++)
      Pf[j][ks] = *(const bf16x8*)&Pb[(j * 16 + l16) * 64 + ks * 32 + quad * 8];

  f32x4 zero = {0.f, 0.f, 0.f, 0.f};
  int e1 = lane >> 1, noff = (lane & 1) * 8;
  int nbase = nc * 128 + wave * 32;
  int orow = lane >> 3, ocol = (lane & 7) * 8;

  union { uint4 q; unsigned short s[8]; } g0, g1, c0, c1;
  g0.q = *(const uint4*)&V[(size_t)e1 * NPIX + nbase + noff];
  g1.q = *(const uint4*)&V[(size_t)(e1 + 32) * NPIX + nbase + noff];
#pragma unroll
  for (int nt = 0; nt < 2; nt++) {
    int n0 = nbase + nt * 16;
    c0 = g0; c1 = g1;
    if (nt < 1) {
      g0.q = *(const uint4*)&V[(size_t)e1 * NPIX + n0 + 16 + noff];
      g1.q = *(const uint4*)&V[(size_t)(e1 + 32) * NPIX + n0 + 16 + noff];
    }
    for (int jj = 0; jj < 8; jj++) {
      Vt[wave][noff + jj][e1]      = c0.s[jj];
      Vt[wave][noff + jj][e1 + 32] = c1.s[jj];
    }
    bf16x8 Af0 = *(const bf16x8*)&Vt[wave][l16][quad * 8];
    bf16x8 Af1 = *(const bf16x8*)&Vt[wave][l16][32 + quad * 8];
    f32x4 oacc[4];
    for (int j = 0; j < 4; j++) {
      oacc[j] = __builtin_amdgcn_mfma_f32_16x16x32_bf16(Af0, Pf[j][0], zero, 0, 0, 0);
      oacc[j] = __builtin_amdgcn_mfma_f32_16x16x32_bf16(Af1, Pf[j][1], oacc[j], 0, 0, 0);
    }
    for (int j = 0; j < 4; j++)
      for (int r = 0; r < 4; r++)
        Ot[wave][quad * 4 + r][j * 16 + l16] = f2bf(oacc[j][r]);
    uint4 o0 = *(const uint4*)&Ot[wave][orow][ocol];
    uint4 o1 = *(const uint4*)&Ot[wave][orow + 8][ocol];
    *(uint4*)&Ob[(size_t)(n0 + orow) * CCH + ocol] = o0;
    *(uint4*)&Ob[(size_t)(n0 + orow + 8) * CCH + ocol] = o1;
  }
}

// ---------------------------------------------------------------------------
extern "C" void kernel_launch(void* const* d_in, const int* in_sizes, int n_in,
                              void* d_out, int out_size, void* d_ws, size_t ws_size,
                              hipStream_t stream) {
  const float* x     = (const float*)d_in[0];
  const float* Wq    = (const float*)d_in[1];
  const float* Wk    = (const float*)d_in[2];
  const float* Wv    = (const float*)d_in[3];
  const float* dww   = (const float*)d_in[4];
  const float* gamma = (const float*)d_in[5];
  const float* beta  = (const float*)d_in[6];
  const float* temp  = (const float*)d_in[7];
  const float* Wp    = (const float*)d_in[8];
  const float* bp    = (const float*)d_in[9];
  float* out = (float*)d_out;

  char* ws = (char*)d_ws;
  unsigned short* wcat = (unsigned short*)ws;             // [1536,512] bf16
  unsigned short* wpb  = wcat + (size_t)QKV_M * CCH;      // [512,512] bf16
  float* s1 = (float*)(wpb + (size_t)CCH * CCH);
  float* s2 = s1 + CCH;
  unsigned short* Pbuf = (unsigned short*)(s2 + CCH);     // [B*H,64,64] bf16, 2MB
  char* dyn = (char*)(Pbuf + (size_t)BATCH * HEADS * 64 * 64);
  size_t fixed = (size_t)(dyn - ws);
  size_t per_b = ((size_t)NPIX * CCH + (size_t)QKV_M * NPIX) * 2;  // 4 MB/batch
  int BC = BATCH;
  while (BC > 1 && fixed + (size_t)BC * per_b > ws_size) BC >>= 1;
  unsigned short* xT  = (unsigned short*)dyn;                  // [BC,N,C]; reused as aoT
  unsigned short* qkv = xT + (size_t)BC * NPIX * CCH;          // [BC,1536,N]

  prep_w<<<CCH * CCH / 1024, 256, 0, stream>>>(Wq, Wk, Wv, Wp, wcat, wpb, s1, s2);
  dw_stats<<<dim3(CCH, BATCH), 256, 0, stream>>>(x, dww, s1, s2);

  for (int b0 = 0; b0 < BATCH; b0 += BC) {
    const float* xc = x + (size_t)b0 * CCH * NPIX;
    float* outc = out + (size_t)b0 * CCH * NPIX;
    transpose_f2b<<<dim3(NPIX / 64, CCH / 64, BC), 256, 0, stream>>>(xc, xT);
    gemm_bt128<<<dim3(NPIX / 128, QKV_M / 128, BC), 256, 0, stream>>>(
        wcat, xT, qkv, QKV_M, NPIX, CCH);
    attn_s<<<BC * HEADS, 256, 0, stream>>>(qkv, temp, Pbuf);
    gate_apply<<<dim3(CCH, BC), 256, 0, stream>>>(xc, dww, s1, s2, gamma, beta, qkv);
    attn_o<<<BC * HEADS * 8, 256, 0, stream>>>(qkv, Pbuf, xT);
    gemm_bt<true><<<dim3(NPIX / 256, CCH / 256, BC), 512, 0, stream>>>(
        wpb, xT, outc, bp, CCH, NPIX, CCH);
  }
}

// Round 12
// 302.021 us; speedup vs baseline: 1.1374x; 1.0325x over previous
//
#include <hip/hip_runtime.h>
#include <stdint.h>

#define BATCH 32
#define CCH   512
#define NPIX  1024
#define HEADS 8
#define QKV_M 1536   // q rows 0-511, k rows 512-1023, v rows 1024-1535

typedef short bf16x8 __attribute__((ext_vector_type(8)));
typedef float f32x4 __attribute__((ext_vector_type(4)));
typedef unsigned short u16x8 __attribute__((ext_vector_type(8)));

__device__ inline float bf2f(unsigned short u) {
  union { float f; uint32_t i; } t; t.i = ((uint32_t)u) << 16; return t.f;
}
__device__ inline unsigned short f2bf(float f) {
  union { float f; uint32_t u; } t; t.f = f;
  uint32_t u = t.u;
  return (unsigned short)((u + 0x7FFFu + ((u >> 16) & 1u)) >> 16);
}

// async global->LDS, 16B per lane; LDS dest = wave-uniform base + lane*16
__device__ inline void gl_lds16(const unsigned short* g, unsigned short* l) {
  __builtin_amdgcn_global_load_lds(
      (const __attribute__((address_space(1))) uint32_t*)g,
      (__attribute__((address_space(3))) uint32_t*)l, 16, 0, 0);
}

// ---------------- prep_w: weights fp32->bf16 AND zero s1/s2 ------------------
__global__ void prep_w(const float* __restrict__ Wq, const float* __restrict__ Wk,
                       const float* __restrict__ Wv, const float* __restrict__ Wp,
                       unsigned short* __restrict__ wcat,
                       unsigned short* __restrict__ wpb,
                       float* __restrict__ s1, float* __restrict__ s2) {
  if (blockIdx.x == 0) {
    const f32x4 z4 = {0.f, 0.f, 0.f, 0.f};
    if (threadIdx.x < 128) ((f32x4*)s1)[threadIdx.x] = z4;
    else ((f32x4*)s2)[threadIdx.x - 128] = z4;
  }
  int i = (blockIdx.x * 256 + threadIdx.x) * 4;   // over CCH*CCH = 262144
  union { ushort4 u4; unsigned short s[4]; } o;
  f32x4 a;
  a = *(const f32x4*)&Wq[i];
  for (int j = 0; j < 4; j++) o.s[j] = f2bf(a[j]);
  *(ushort4*)&wcat[i] = o.u4;
  a = *(const f32x4*)&Wk[i];
  for (int j = 0; j < 4; j++) o.s[j] = f2bf(a[j]);
  *(ushort4*)&wcat[CCH * CCH + i] = o.u4;
  a = *(const f32x4*)&Wv[i];
  for (int j = 0; j < 4; j++) o.s[j] = f2bf(a[j]);
  *(ushort4*)&wcat[2 * CCH * CCH + i] = o.u4;
  a = *(const f32x4*)&Wp[i];
  for (int j = 0; j < 4; j++) o.s[j] = f2bf(a[j]);
  *(ushort4*)&wpb[i] = o.u4;
}

// ---------------- transpose fp32 [b,C,N] -> bf16 [b,N,C] ---------------------
__global__ void transpose_f2b(const float* __restrict__ in,
                              unsigned short* __restrict__ out) {
  __shared__ float tile[64][65];
  const int b  = blockIdx.z;
  const int p0 = blockIdx.x * 64;   // pixel base
  const int c0 = blockIdx.y * 64;   // channel base
  const float* inb = in + (size_t)b * CCH * NPIX;
  unsigned short* outb = out + (size_t)b * NPIX * CCH;
  const int t = threadIdx.x;
  const int cr = t >> 2, tl = t & 3;
#pragma unroll
  for (int j = 0; j < 4; ++j) {
    const int off = j * 16 + tl * 4;
    f32x4 v = *(const f32x4*)&inb[(size_t)(c0 + cr) * NPIX + p0 + off];
    tile[cr][off + 0] = v[0];
    tile[cr][off + 1] = v[1];
    tile[cr][off + 2] = v[2];
    tile[cr][off + 3] = v[3];
  }
  __syncthreads();
  const int pr = t >> 3, cc = (t & 7) * 8;
#pragma unroll
  for (int pass = 0; pass < 2; ++pass) {
    const int p = pr + pass * 32;
    union { u16x8 v; unsigned short s[8]; } o;
#pragma unroll
    for (int j = 0; j < 8; ++j) o.s[j] = f2bf(tile[cc + j][p]);
    *(u16x8*)&outb[(size_t)(p0 + p) * CCH + c0 + cc] = o.v;
  }
}

// ---------------- gemm_bt128: bf16-out GEMM, 128x128 tile --------------------
// Frozen (rounds 1-11): three schedule structures + tile-size/TLP variants all
// land 72-84us at this K=512 shape; MfmaUtil pinned ~25-29%. Kept over 256^2
// for lower FETCH (32 vs 44 MB).
__launch_bounds__(256, 2)
__global__ void gemm_bt128(const unsigned short* __restrict__ A,
                           const unsigned short* __restrict__ X,
                           unsigned short* __restrict__ Cout,
                           int M, int N, int K) {
  __shared__ __align__(16) unsigned short As[2][128 * 64];
  __shared__ __align__(16) unsigned short Bs[2][128 * 64];
  const int b  = blockIdx.z;
  const int m0 = blockIdx.y * 128;
  const int n0 = blockIdx.x * 128;
  const unsigned short* Xb = X + (size_t)b * N * K;
  const int tid  = threadIdx.x;
  const int lane = tid & 63;
  const int wave = tid >> 6;        // 0..3
  const int wm = wave >> 1;         // 0..1 (M half: 64 rows)
  const int wn = wave & 1;          // 0..1 (N half: 64 cols)
  const int quad = lane >> 4, l16 = lane & 15;

  f32x4 acc[4][4];
  const f32x4 zero = {0.f, 0.f, 0.f, 0.f};
#pragma unroll
  for (int i = 0; i < 4; i++)
#pragma unroll
    for (int j = 0; j < 4; j++) acc[i][j] = zero;

  const int r8  = lane >> 3;
  const int swk = ((lane & 7) ^ r8) * 8;
  const unsigned short* Ag = A  + (size_t)(m0 + wave * 32 + r8) * K + swk;
  const unsigned short* Xg = Xb + (size_t)(n0 + wave * 32 + r8) * K + swk;

  const int NT = K >> 6;            // K-tiles of 64

  auto stage = [&](int kt, int bsel) {
    unsigned short* Al = &As[bsel][wave * 32 * 64];
    unsigned short* Bl = &Bs[bsel][wave * 32 * 64];
    const unsigned short* Agk = Ag + kt * 64;
    const unsigned short* Xgk = Xg + kt * 64;
#pragma unroll
    for (int i = 0; i < 4; ++i) {
      gl_lds16(Agk + (size_t)i * 8 * K, Al + i * 8 * 64);
      gl_lds16(Xgk + (size_t)i * 8 * K, Bl + i * 8 * 64);
    }
  };

  stage(0, 0);
  if (NT > 1) stage(1, 1);
  asm volatile("s_waitcnt vmcnt(8)" ::: "memory");
  __builtin_amdgcn_s_barrier();

  for (int t = 0; t < NT; ++t) {
    const int cur = t & 1;
    const unsigned short* Asl = As[cur];
    const unsigned short* Bsl = Bs[cur];

    {
      bf16x8 a0[4], b0[4], a1[4], b1[4];
      const int ch0 = ((0 * 4 + quad) ^ (l16 & 7)) * 8;
      const int ch1 = ((1 * 4 + quad) ^ (l16 & 7)) * 8;
#pragma unroll
      for (int ii = 0; ii < 4; ++ii) {
        a0[ii] = *(const bf16x8*)&Asl[(wm * 64 + ii * 16 + l16) * 64 + ch0];
        a1[ii] = *(const bf16x8*)&Asl[(wm * 64 + ii * 16 + l16) * 64 + ch1];
      }
#pragma unroll
      for (int jj = 0; jj < 4; ++jj) {
        b0[jj] = *(const bf16x8*)&Bsl[(wn * 64 + jj * 16 + l16) * 64 + ch0];
        b1[jj] = *(const bf16x8*)&Bsl[(wn * 64 + jj * 16 + l16) * 64 + ch1];
      }
#pragma unroll
      for (int ii = 0; ii < 4; ++ii)
#pragma unroll
        for (int jj = 0; jj < 4; ++jj)
          acc[ii][jj] = __builtin_amdgcn_mfma_f32_16x16x32_bf16(
              a0[ii], b0[jj], acc[ii][jj], 0, 0, 0);
#pragma unroll
      for (int ii = 0; ii < 4; ++ii)
#pragma unroll
        for (int jj = 0; jj < 4; ++jj)
          acc[ii][jj] = __builtin_amdgcn_mfma_f32_16x16x32_bf16(
              a1[ii], b1[jj], acc[ii][jj], 0, 0, 0);
    }

    __builtin_amdgcn_s_barrier();
    if (t + 2 < NT) {
      stage(t + 2, cur);
      asm volatile("s_waitcnt vmcnt(8)" ::: "memory");
    } else if (t + 1 < NT) {
      asm volatile("s_waitcnt vmcnt(0)" ::: "memory");
    }
    __builtin_amdgcn_s_barrier();
  }

  // C/D layout: row = quad*4+reg, col = l16
#pragma unroll
  for (int i = 0; i < 4; ++i) {
#pragma unroll
    for (int r = 0; r < 4; ++r) {
      const int gm = m0 + wm * 64 + i * 16 + quad * 4 + r;
      unsigned short* Co = Cout + (size_t)b * M * N + (size_t)gm * N +
                           n0 + wn * 64 + l16;
#pragma unroll
      for (int j = 0; j < 4; ++j) Co[j * 16] = f2bf(acc[i][j][r]);
    }
  }
}

// ---------------- gemm_bt: 256^2 tile (Wp projection; fp32-write-floor) ------
template <bool OUT_F32>
__launch_bounds__(512, 2)
__global__ void gemm_bt(const unsigned short* __restrict__ A,
                        const unsigned short* __restrict__ X,
                        void* __restrict__ Cout,
                        const float* __restrict__ bias,
                        int M, int N, int K) {
  __shared__ __align__(16) unsigned short As[2][256 * 64];
  __shared__ __align__(16) unsigned short Bs[2][256 * 64];
  const int b  = blockIdx.z;
  const int m0 = blockIdx.y * 256;
  const int n0 = blockIdx.x * 256;
  const unsigned short* Xb = X + (size_t)b * N * K;
  const int tid  = threadIdx.x;
  const int lane = tid & 63;
  const int wave = tid >> 6;        // 0..7
  const int wm = wave >> 2;
  const int wn = wave & 3;
  const int quad = lane >> 4, l16 = lane & 15;

  f32x4 acc[8][4];
  const f32x4 zero = {0.f, 0.f, 0.f, 0.f};
#pragma unroll
  for (int i = 0; i < 8; i++)
#pragma unroll
    for (int j = 0; j < 4; j++) acc[i][j] = zero;

  const int r8  = lane >> 3;
  const int swk = ((lane & 7) ^ r8) * 8;
  const unsigned short* Ag = A  + (size_t)(m0 + wave * 32 + r8) * K + swk;
  const unsigned short* Xg = Xb + (size_t)(n0 + wave * 32 + r8) * K + swk;

  const int NT = K >> 6;

  auto stage = [&](int kt, int bsel) {
    unsigned short* Al = &As[bsel][wave * 32 * 64];
    unsigned short* Bl = &Bs[bsel][wave * 32 * 64];
    const unsigned short* Agk = Ag + kt * 64;
    const unsigned short* Xgk = Xg + kt * 64;
#pragma unroll
    for (int i = 0; i < 4; ++i) {
      gl_lds16(Agk + (size_t)i * 8 * K, Al + i * 8 * 64);
      gl_lds16(Xgk + (size_t)i * 8 * K, Bl + i * 8 * 64);
    }
  };

  stage(0, 0);
  if (NT > 1) stage(1, 1);
  asm volatile("s_waitcnt vmcnt(8)" ::: "memory");
  __builtin_amdgcn_s_barrier();

  for (int t = 0; t < NT; ++t) {
    const int cur = t & 1;
    const unsigned short* Asl = As[cur];
    const unsigned short* Bsl = Bs[cur];

    {
      bf16x8 a0[8], b0[4];
      const int ch0 = ((0 * 4 + quad) ^ (l16 & 7)) * 8;
#pragma unroll
      for (int ii = 0; ii < 8; ++ii)
        a0[ii] = *(const bf16x8*)&Asl[(wm * 128 + ii * 16 + l16) * 64 + ch0];
#pragma unroll
      for (int jj = 0; jj < 4; ++jj)
        b0[jj] = *(const bf16x8*)&Bsl[(wn * 64 + jj * 16 + l16) * 64 + ch0];

      bf16x8 a1[8], b1[4];
      const int ch1 = ((1 * 4 + quad) ^ (l16 & 7)) * 8;
#pragma unroll
      for (int ii = 0; ii < 8; ++ii)
        a1[ii] = *(const bf16x8*)&Asl[(wm * 128 + ii * 16 + l16) * 64 + ch1];
#pragma unroll
      for (int jj = 0; jj < 4; ++jj)
        b1[jj] = *(const bf16x8*)&Bsl[(wn * 64 + jj * 16 + l16) * 64 + ch1];

#pragma unroll
      for (int ii = 0; ii < 8; ++ii)
#pragma unroll
        for (int jj = 0; jj < 4; ++jj)
          acc[ii][jj] = __builtin_amdgcn_mfma_f32_16x16x32_bf16(
              a0[ii], b0[jj], acc[ii][jj], 0, 0, 0);
#pragma unroll
      for (int ii = 0; ii < 8; ++ii)
#pragma unroll
        for (int jj = 0; jj < 4; ++jj)
          acc[ii][jj] = __builtin_amdgcn_mfma_f32_16x16x32_bf16(
              a1[ii], b1[jj], acc[ii][jj], 0, 0, 0);
    }

    __builtin_amdgcn_s_barrier();
    if (t + 2 < NT) {
      stage(t + 2, cur);
      asm volatile("s_waitcnt vmcnt(8)" ::: "memory");
    } else if (t + 1 < NT) {
      asm volatile("s_waitcnt vmcnt(0)" ::: "memory");
    }
    __builtin_amdgcn_s_barrier();
  }

  // C/D layout: row = quad*4+reg, col = l16
#pragma unroll
  for (int i = 0; i < 8; ++i) {
#pragma unroll
    for (int r = 0; r < 4; ++r) {
      const int gm = m0 + wm * 128 + i * 16 + quad * 4 + r;
      if constexpr (OUT_F32) {
        const float bv = bias[gm];
        float* Co = (float*)Cout + (size_t)b * M * N + (size_t)gm * N +
                    n0 + wn * 64 + l16;
#pragma unroll
        for (int j = 0; j < 4; ++j) Co[j * 16] = acc[i][j][r] + bv;
      } else {
        unsigned short* Co = (unsigned short*)Cout + (size_t)b * M * N +
                             (size_t)gm * N + n0 + wn * 64 + l16;
#pragma unroll
        for (int j = 0; j < 4; ++j) Co[j * 16] = f2bf(acc[i][j][r]);
      }
    }
  }
}

// ---------------- depthwise 3x3 per-channel stats (sum, sumsq) ---------------
// Round-12: zero-padded plane (34 rows x stride 35) -> conv = 9 unconditional
// FMAs, no bounds checks (~250->~70 VALU/thread). Stride 35: conv-read bank
// = (3h+w)%32 -> <=2 lanes/bank (free). Border zeros reproduce the original
// out-of-range-tap=0 semantics exactly.
__global__ void dw_stats(const float* __restrict__ x,
                         const float* __restrict__ wgt,
                         float* __restrict__ s1, float* __restrict__ s2) {
  int c = blockIdx.x, b = blockIdx.y;
  __shared__ float plane[34 * 35];   // rows h=-1..32, stride 35
  const float* xp = x + ((size_t)b * CCH + c) * NPIX;
  const int t = threadIdx.x;
  if (t < 132) {                     // zero the halo border
    int idx;
    if (t < 34) idx = t;                              // row 0
    else if (t < 68) idx = 33 * 35 + (t - 34);        // row 33
    else if (t < 100) idx = (t - 67) * 35;            // col 0, rows 1..32
    else idx = (t - 99) * 35 + 33;                    // col 33, rows 1..32
    plane[idx] = 0.f;
  }
  {
    f32x4 v = *(const f32x4*)&xp[t * 4];
    const int h = t >> 3, w0 = (t & 7) * 4;
    float* pr = &plane[(h + 1) * 35 + w0 + 1];
    pr[0] = v[0]; pr[1] = v[1]; pr[2] = v[2]; pr[3] = v[3];
  }
  __syncthreads();
  float w[9];
  for (int i = 0; i < 9; i++) w[i] = wgt[c * 9 + i];
  float a1 = 0.f, a2 = 0.f;
#pragma unroll
  for (int pi = 0; pi < 4; pi++) {
    int p = t + pi * 256;
    int h = p >> 5, wc = p & 31;
    const float* base = &plane[(h + 1) * 35 + wc + 1];
    float v = w[0] * base[-36] + w[1] * base[-35] + w[2] * base[-34] +
              w[3] * base[-1]  + w[4] * base[0]   + w[5] * base[1] +
              w[6] * base[34]  + w[7] * base[35]  + w[8] * base[36];
    a1 += v; a2 += v * v;
  }
  for (int off = 32; off > 0; off >>= 1) {
    a1 += __shfl_down(a1, off);
    a2 += __shfl_down(a2, off);
  }
  __shared__ float r1[4], r2[4];
  int wv = threadIdx.x >> 6;
  if ((threadIdx.x & 63) == 0) { r1[wv] = a1; r2[wv] = a2; }
  __syncthreads();
  if (threadIdx.x == 0) {
    atomicAdd(&s1[c], r1[0] + r1[1] + r1[2] + r1[3]);
    atomicAdd(&s2[c], r2[0] + r2[1] + r2[2] + r2[3]);
  }
}

// ---------------- gate: v (rows 1024..1535 of qkv) *= SiLU(BN(conv(x))) ------
// Round-12: same zero-padded stride-35 plane as dw_stats (conv bank profile
// for this kernel's lane map: (3h+4j)%32 -> <=2 lanes/bank, free; the
// round-10 stride-33 pad is superseded). Vectorized I/O kept.
__global__ void gate_apply(const float* __restrict__ x,
                           const float* __restrict__ wgt,
                           const float* __restrict__ s1, const float* __restrict__ s2,
                           const float* __restrict__ gamma,
                           const float* __restrict__ beta,
                           unsigned short* __restrict__ qkv) {
  int c = blockIdx.x, b = blockIdx.y;
  __shared__ float plane[34 * 35];
  const float* xp = x + ((size_t)b * CCH + c) * NPIX;
  const int t = threadIdx.x;
  if (t < 132) {
    int idx;
    if (t < 34) idx = t;
    else if (t < 68) idx = 33 * 35 + (t - 34);
    else if (t < 100) idx = (t - 67) * 35;
    else idx = (t - 99) * 35 + 33;
    plane[idx] = 0.f;
  }
  const int h = t >> 3, w0 = (t & 7) * 4;
  {
    f32x4 v = *(const f32x4*)&xp[t * 4];
    float* pr = &plane[(h + 1) * 35 + w0 + 1];
    pr[0] = v[0]; pr[1] = v[1]; pr[2] = v[2]; pr[3] = v[3];
  }
  __syncthreads();
  float w[9];
  for (int i = 0; i < 9; i++) w[i] = wgt[c * 9 + i];
  const float invn = 1.f / 32768.f;
  float mean = s1[c] * invn;
  float var = fmaxf(s2[c] * invn - mean * mean, 0.f);
  float rstd = rsqrtf(var + 1e-5f);
  float ga = gamma[c], be = beta[c];

  unsigned short* vp = qkv + ((size_t)b * QKV_M + 2 * CCH + c) * NPIX + h * 32 + w0;
  union { ushort4 q; unsigned short s[4]; } vv;
  vv.q = *(const ushort4*)vp;
#pragma unroll
  for (int i = 0; i < 4; ++i) {
    const float* base = &plane[(h + 1) * 35 + (w0 + i) + 1];
    float val = w[0] * base[-36] + w[1] * base[-35] + w[2] * base[-34] +
                w[3] * base[-1]  + w[4] * base[0]   + w[5] * base[1] +
                w[6] * base[34]  + w[7] * base[35]  + w[8] * base[36];
    float g = (val - mean) * rstd * ga + be;
    float sg = g / (1.f + __expf(-g));      // SiLU
    vv.s[i] = f2bf(bf2f(vv.s[i]) * sg);
  }
  *(ushort4*)vp = vv.q;
}

// ---------------- attn_s: S=QK^T (+ fused l2norm via QQ^T/KK^T diag),
//                  softmax -> P [bh][64][64] bf16 -------------------------------
__launch_bounds__(256)
__global__ void attn_s(const unsigned short* __restrict__ qkv,
                       const float* __restrict__ temp,
                       unsigned short* __restrict__ P) {
  int bh = blockIdx.x;
  int b = bh >> 3, h = bh & 7;
  const unsigned short* Q = qkv + ((size_t)b * QKV_M + h * 64) * NPIX;
  const unsigned short* K = Q + (size_t)CCH * NPIX;
  int tid = threadIdx.x, lane = tid & 63, wave = tid >> 6;
  int quad = lane >> 4, l16 = lane & 15;

  __shared__ __align__(16) float Sf[64][65];
  __shared__ float qq[64], kk[64], invq[64], invk[64];
  __shared__ float redm[4][64], reds[4][64];

  f32x4 zero = {0.f, 0.f, 0.f, 0.f};
  f32x4 acc[4], accQ = zero, accK = zero;
  for (int j = 0; j < 4; j++) acc[j] = zero;
  for (int n0 = 0; n0 < NPIX; n0 += 32) {
    bf16x8 a  = *(const bf16x8*)&Q[(size_t)(wave * 16 + l16) * NPIX + n0 + quad * 8];
    bf16x8 ak = *(const bf16x8*)&K[(size_t)(wave * 16 + l16) * NPIX + n0 + quad * 8];
    accQ = __builtin_amdgcn_mfma_f32_16x16x32_bf16(a, a, accQ, 0, 0, 0);
    accK = __builtin_amdgcn_mfma_f32_16x16x32_bf16(ak, ak, accK, 0, 0, 0);
    for (int j = 0; j < 4; j++) {
      bf16x8 bb = *(const bf16x8*)&K[(size_t)(j * 16 + l16) * NPIX + n0 + quad * 8];
      acc[j] = __builtin_amdgcn_mfma_f32_16x16x32_bf16(a, bb, acc[j], 0, 0, 0);
    }
  }
  for (int j = 0; j < 4; j++)
    for (int r = 0; r < 4; r++)
      Sf[wave * 16 + quad * 4 + r][j * 16 + l16] = acc[j][r];
  for (int r = 0; r < 4; r++)
    if (l16 == quad * 4 + r) {
      qq[wave * 16 + l16] = accQ[r];
      kk[wave * 16 + l16] = accK[r];
    }
  __syncthreads();
  if (tid < 64) invq[tid] = 1.f / fmaxf(sqrtf(qq[tid]), 1e-12f);
  else if (tid < 128) invk[tid - 64] = 1.f / fmaxf(sqrtf(kk[tid - 64]), 1e-12f);
  __syncthreads();

  int row = tid & 63, seg = tid >> 6;
  float fq = temp[h] * invq[row];
  float v[16], pm = -1e30f;
  for (int i = 0; i < 16; i++) {
    v[i] = Sf[row][seg * 16 + i] * fq * invk[seg * 16 + i];
    pm = fmaxf(pm, v[i]);
  }
  redm[seg][row] = pm;
  __syncthreads();
  float m = fmaxf(fmaxf(redm[0][row], redm[1][row]),
                  fmaxf(redm[2][row], redm[3][row]));
  float ps = 0.f;
  for (int i = 0; i < 16; i++) { v[i] = __expf(v[i] - m); ps += v[i]; }
  reds[seg][row] = ps;
  __syncthreads();
  float inv = 1.f / (reds[0][row] + reds[1][row] + reds[2][row] + reds[3][row]);
  union { uint4 q4[2]; unsigned short s[16]; } u;
  for (int i = 0; i < 16; i++) u.s[i] = f2bf(v[i] * inv);
  unsigned short* Pp = P + ((size_t)bh * 64 + row) * 64 + seg * 16;
  *(uint4*)&Pp[0] = u.q4[0];
  *(uint4*)&Pp[8] = u.q4[1];
}

// ---------------- attn_o: O^T[n][d] = sum_e V^T[n][e] P[d][e] ----------------
__launch_bounds__(256)
__global__ void attn_o(const unsigned short* __restrict__ qkv,
                       const unsigned short* __restrict__ P,
                       unsigned short* __restrict__ aoT) {
  int blk = blockIdx.x;
  int nc = blk & 7, bh = blk >> 3;
  int b = bh >> 3, h = bh & 7;
  const unsigned short* V = qkv + ((size_t)b * QKV_M + 2 * CCH + h * 64) * NPIX;
  unsigned short* Ob = aoT + (size_t)b * NPIX * CCH + h * 64;
  int tid = threadIdx.x, lane = tid & 63, wave = tid >> 6;
  int quad = lane >> 4, l16 = lane & 15;

  __shared__ __align__(16) unsigned short Vt[4][16][72];
  __shared__ __align__(16) unsigned short Ot[4][16][72];

  const unsigned short* Pb = P + (size_t)bh * 64 * 64;
  bf16x8 Pf[4][2];
  for (int j = 0; j < 4; j++)
    for (int ks = 0; ks < 2; ks++)
      Pf[j][ks] = *(const bf16x8*)&Pb[(j * 16 + l16) * 64 + ks * 32 + quad * 8];

  f32x4 zero = {0.f, 0.f, 0.f, 0.f};
  int e1 = lane >> 1, noff = (lane & 1) * 8;
  int nbase = nc * 128 + wave * 32;
  int orow = lane >> 3, ocol = (lane & 7) * 8;

  union { uint4 q; unsigned short s[8]; } g0, g1, c0, c1;
  g0.q = *(const uint4*)&V[(size_t)e1 * NPIX + nbase + noff];
  g1.q = *(const uint4*)&V[(size_t)(e1 + 32) * NPIX + nbase + noff];
#pragma unroll
  for (int nt = 0; nt < 2; nt++) {
    int n0 = nbase + nt * 16;
    c0 = g0; c1 = g1;
    if (nt < 1) {
      g0.q = *(const uint4*)&V[(size_t)e1 * NPIX + n0 + 16 + noff];
      g1.q = *(const uint4*)&V[(size_t)(e1 + 32) * NPIX + n0 + 16 + noff];
    }
    for (int jj = 0; jj < 8; jj++) {
      Vt[wave][noff + jj][e1]      = c0.s[jj];
      Vt[wave][noff + jj][e1 + 32] = c1.s[jj];
    }
    bf16x8 Af0 = *(const bf16x8*)&Vt[wave][l16][quad * 8];
    bf16x8 Af1 = *(const bf16x8*)&Vt[wave][l16][32 + quad * 8];
    f32x4 oacc[4];
    for (int j = 0; j < 4; j++) {
      oacc[j] = __builtin_amdgcn_mfma_f32_16x16x32_bf16(Af0, Pf[j][0], zero, 0, 0, 0);
      oacc[j] = __builtin_amdgcn_mfma_f32_16x16x32_bf16(Af1, Pf[j][1], oacc[j], 0, 0, 0);
    }
    for (int j = 0; j < 4; j++)
      for (int r = 0; r < 4; r++)
        Ot[wave][quad * 4 + r][j * 16 + l16] = f2bf(oacc[j][r]);
    uint4 o0 = *(const uint4*)&Ot[wave][orow][ocol];
    uint4 o1 = *(const uint4*)&Ot[wave][orow + 8][ocol];
    *(uint4*)&Ob[(size_t)(n0 + orow) * CCH + ocol] = o0;
    *(uint4*)&Ob[(size_t)(n0 + orow + 8) * CCH + ocol] = o1;
  }
}

// ---------------------------------------------------------------------------
extern "C" void kernel_launch(void* const* d_in, const int* in_sizes, int n_in,
                              void* d_out, int out_size, void* d_ws, size_t ws_size,
                              hipStream_t stream) {
  const float* x     = (const float*)d_in[0];
  const float* Wq    = (const float*)d_in[1];
  const float* Wk    = (const float*)d_in[2];
  const float* Wv    = (const float*)d_in[3];
  const float* dww   = (const float*)d_in[4];
  const float* gamma = (const float*)d_in[5];
  const float* beta  = (const float*)d_in[6];
  const float* temp  = (const float*)d_in[7];
  const float* Wp    = (const float*)d_in[8];
  const float* bp    = (const float*)d_in[9];
  float* out = (float*)d_out;

  char* ws = (char*)d_ws;
  unsigned short* wcat = (unsigned short*)ws;             // [1536,512] bf16
  unsigned short* wpb  = wcat + (size_t)QKV_M * CCH;      // [512,512] bf16
  float* s1 = (float*)(wpb + (size_t)CCH * CCH);
  float* s2 = s1 + CCH;
  unsigned short* Pbuf = (unsigned short*)(s2 + CCH);     // [B*H,64,64] bf16, 2MB
  char* dyn = (char*)(Pbuf + (size_t)BATCH * HEADS * 64 * 64);
  size_t fixed = (size_t)(dyn - ws);
  size_t per_b = ((size_t)NPIX * CCH + (size_t)QKV_M * NPIX) * 2;  // 4 MB/batch
  int BC = BATCH;
  while (BC > 1 && fixed + (size_t)BC * per_b > ws_size) BC >>= 1;
  unsigned short* xT  = (unsigned short*)dyn;                  // [BC,N,C]; reused as aoT
  unsigned short* qkv = xT + (size_t)BC * NPIX * CCH;          // [BC,1536,N]

  prep_w<<<CCH * CCH / 1024, 256, 0, stream>>>(Wq, Wk, Wv, Wp, wcat, wpb, s1, s2);
  dw_stats<<<dim3(CCH, BATCH), 256, 0, stream>>>(x, dww, s1, s2);

  for (int b0 = 0; b0 < BATCH; b0 += BC) {
    const float* xc = x + (size_t)b0 * CCH * NPIX;
    float* outc = out + (size_t)b0 * CCH * NPIX;
    transpose_f2b<<<dim3(NPIX / 64, CCH / 64, BC), 256, 0, stream>>>(xc, xT);
    gemm_bt128<<<dim3(NPIX / 128, QKV_M / 128, BC), 256, 0, stream>>>(
        wcat, xT, qkv, QKV_M, NPIX, CCH);
    attn_s<<<BC * HEADS, 256, 0, stream>>>(qkv, temp, Pbuf);
    gate_apply<<<dim3(CCH, BC), 256, 0, stream>>>(xc, dww, s1, s2, gamma, beta, qkv);
    attn_o<<<BC * HEADS * 8, 256, 0, stream>>>(qkv, Pbuf, xT);
    gemm_bt<true><<<dim3(NPIX / 256, CCH / 256, BC), 512, 0, stream>>>(
        wpb, xT, outc, bp, CCH, NPIX, CCH);
  }
}